// Round 10
// baseline (376.375 us; speedup 1.0000x reference)
//
#include <hip/hip_runtime.h>
#include <hip/hip_bf16.h>

#define NN 50000
#define NE 800000
#define DD 128
#define KSEL 25000
#define NBK 391                 // buckets of 128 nodes (graph build)
#define NBLKA 98                // (NE+8191)/8192
#define AB 12500                // agg node-blocks (4 nodes/block)

typedef unsigned int uint32;
typedef unsigned short ushort16;

__device__ __forceinline__ float sigmoidf(float x){ return 1.f/(1.f+__expf(-x)); }

__device__ __forceinline__ unsigned short f2b(float f){
  union{float f; unsigned u;} v; v.f=f;
  unsigned r=(v.u + 0x7fffu + ((v.u>>16)&1u))>>16;
  return (unsigned short)r;
}

__device__ __forceinline__ void addbf2(float&lo,float&hi,uint32 u,float w){
  lo+=__uint_as_float(u<<16)*w;
  hi+=__uint_as_float(u&0xffff0000u)*w;
}

// ============ prep: transpose Wbil + zero ctrl/hists/btot (1 dispatch) ======
__global__ __launch_bounds__(256) void k_prep(const float* __restrict__ W,
    float* __restrict__ Wt, int* __restrict__ zspan, int* __restrict__ btot){
  int i=blockIdx.x*256+threadIdx.x;      // 64 blocks -> 16384 threads
  if(i<DD*DD) Wt[i]=W[(i&127)*DD+(i>>7)];
  if(i<8512) zspan[i]=0;                 // ctrl(256B)+hist0+hist1+hist2
  if(i<NBK) btot[i]=0;
}

// ================= graph build: bucketed counting sort =================
__global__ __launch_bounds__(1024) void k_bcount(const int* __restrict__ dst,
    int* __restrict__ btot, int* __restrict__ blkcnt){
  __shared__ int h[NBK];
  int tid=threadIdx.x;
  for(int i=tid;i<NBK;i+=1024) h[i]=0;
  __syncthreads();
  int e0=blockIdx.x*8192;
  #pragma unroll
  for(int t=0;t<8;t++){
    int e=e0+t*1024+tid;
    if(e<NE) atomicAdd(&h[dst[e]>>7],1);
  }
  __syncthreads();
  for(int i=tid;i<NBK;i+=1024){
    int c=h[i];
    blkcnt[blockIdx.x*NBK+i]=c;
    if(c) atomicAdd(&btot[i],c);
  }
}

__global__ __launch_bounds__(512) void k_bscan(const int* __restrict__ btot,
    int* __restrict__ boff, const int* __restrict__ blkcnt, int* __restrict__ blkbase,
    int* __restrict__ row_start){
  __shared__ int sdata[512];
  int tid=threadIdx.x;
  int v=(tid<NBK)?btot[tid]:0;
  sdata[tid]=v; __syncthreads();
  for(int off=1;off<512;off<<=1){
    int y=(tid>=off)?sdata[tid-off]:0;
    __syncthreads();
    sdata[tid]+=y;
    __syncthreads();
  }
  int excl=sdata[tid]-v;
  if(tid<NBK) boff[tid]=excl;
  if(tid==NBK-1){ boff[NBK]=excl+v; row_start[NN]=NE; }
  if(tid<NBK){
    int run=excl;
    for(int b=0;b<NBLKA;b++){
      int c=blkcnt[b*NBK+tid];
      blkbase[b*NBK+tid]=run;
      run+=c;
    }
  }
}

// pack: src (17 bits) | local-dst (7 bits) << 17
__global__ __launch_bounds__(1024) void k_bscatter(const int* __restrict__ src,
    const int* __restrict__ dst, const int* __restrict__ blkbase, uint32* __restrict__ pairs){
  __shared__ int cur[NBK];
  int tid=threadIdx.x;
  for(int i=tid;i<NBK;i+=1024) cur[i]=blkbase[blockIdx.x*NBK+i];
  __syncthreads();
  int e0=blockIdx.x*8192;
  #pragma unroll
  for(int t=0;t<8;t++){
    int e=e0+t*1024+tid;
    if(e<NE){
      int d=dst[e];
      int p=atomicAdd(&cur[d>>7],1);
      pairs[p]=(unsigned)src[e] | ((unsigned)(d&127)<<17);
    }
  }
}

__global__ __launch_bounds__(256) void k_bfinal(const uint32* __restrict__ pairs,
    const int* __restrict__ boff, int* __restrict__ row_start,
    float* __restrict__ inv_sq, int* __restrict__ csr_src){
  __shared__ int degl[128];
  __shared__ int cur[128];
  __shared__ int ssum[2];
  int b=blockIdx.x, tid=threadIdx.x;
  int lo=boff[b], hi=boff[b+1];
  if(tid<128) degl[tid]=0;
  __syncthreads();
  for(int e=lo+tid;e<hi;e+=256) atomicAdd(&degl[pairs[e]>>17],1);
  __syncthreads();
  int v=0,x=0;
  if(tid<128){
    v=degl[tid]; x=v;
    #pragma unroll
    for(int off=1;off<64;off<<=1){
      int y=__shfl_up(x,off,64);
      if((tid&63)>=off) x+=y;
    }
    if((tid&63)==63) ssum[tid>>6]=x;
  }
  __syncthreads();
  if(tid<128){
    int incl=x+((tid>=64)?ssum[0]:0);
    int node=b*128+tid;
    int excl=lo+incl-v;
    if(node<NN){
      row_start[node]=excl;
      cur[tid]=excl;
      inv_sq[node]=1.f/sqrtf((float)(v+1));
    }
  }
  __syncthreads();
  for(int e=lo+tid;e<hi;e+=256){
    uint32 u=pairs[e];
    int p=atomicAdd(&cur[u>>17],1);
    csr_src[p]=(int)(u&0x1FFFFu);
  }
}

// ============ fused dual GEMM: h_pos = prelu(feat@Wd+bd); xw1 = h_pos@Wg1 ====
__global__ __launch_bounds__(256) void k_gemm_dual(const float* __restrict__ feat,
    const float* __restrict__ Wd, const float* __restrict__ bd,
    const float* __restrict__ aparam, const float* __restrict__ Wg1,
    float* __restrict__ h_pos, float* __restrict__ xw1){
  __shared__ float Al[96][132];           // 50.7 KB -> 3 blocks/CU
  int tid=threadIdx.x;
  int row0=blockIdx.x*96;
  {
    const float4* A4=(const float4*)(feat+(size_t)row0*DD);
    #pragma unroll
    for(int i=0;i<12;i++){
      int idx=i*256+tid;
      int r=idx>>5, c=(idx&31)*4;
      float4 v=make_float4(0.f,0.f,0.f,0.f);
      if(row0+r<NN) v=A4[idx];
      *(float4*)&Al[r][c]=v;
    }
  }
  __syncthreads();
  int tx=tid&15, ty=tid>>4;
  float acc[6][8];
  #pragma unroll
  for(int i=0;i<6;i++)
    #pragma unroll
    for(int c=0;c<8;c++) acc[i][c]=0.f;
  // pass 1: feat @ Wd
  for(int k=0;k<DD;k+=4){
    float wv[4][8];
    #pragma unroll
    for(int r=0;r<4;r++){
      float4 lo=*(const float4*)&Wd[(size_t)(k+r)*DD+tx*8];
      float4 hi=*(const float4*)&Wd[(size_t)(k+r)*DD+tx*8+4];
      wv[r][0]=lo.x; wv[r][1]=lo.y; wv[r][2]=lo.z; wv[r][3]=lo.w;
      wv[r][4]=hi.x; wv[r][5]=hi.y; wv[r][6]=hi.z; wv[r][7]=hi.w;
    }
    #pragma unroll
    for(int i=0;i<6;i++){
      float4 a=*(const float4*)&Al[ty+16*i][k];
      #pragma unroll
      for(int c=0;c<8;c++)
        acc[i][c]+=a.x*wv[0][c]+a.y*wv[1][c]+a.z*wv[2][c]+a.w*wv[3][c];
    }
  }
  // epilogue 1: bias + prelu, write h_pos, rewrite into Al
  {
    float4 b0=*(const float4*)&bd[tx*8];
    float4 b1=*(const float4*)&bd[tx*8+4];
    float bl[8]={b0.x,b0.y,b0.z,b0.w,b1.x,b1.y,b1.z,b1.w};
    float ap=aparam[0];
    __syncthreads();                      // all pass-1 reads of Al done
    #pragma unroll
    for(int i=0;i<6;i++){
      #pragma unroll
      for(int c=0;c<8;c++){
        float t=acc[i][c]+bl[c];
        acc[i][c]=t>=0.f?t:ap*t;
      }
      int r=row0+ty+16*i;
      float4 q0; q0.x=acc[i][0]; q0.y=acc[i][1]; q0.z=acc[i][2]; q0.w=acc[i][3];
      float4 q1; q1.x=acc[i][4]; q1.y=acc[i][5]; q1.z=acc[i][6]; q1.w=acc[i][7];
      if(r<NN){
        *(float4*)&h_pos[(size_t)r*DD+tx*8]=q0;
        *(float4*)&h_pos[(size_t)r*DD+tx*8+4]=q1;
      }
      *(float4*)&Al[ty+16*i][tx*8]=q0;
      *(float4*)&Al[ty+16*i][tx*8+4]=q1;
    }
  }
  __syncthreads();
  // pass 2: h_pos @ Wg1
  #pragma unroll
  for(int i=0;i<6;i++)
    #pragma unroll
    for(int c=0;c<8;c++) acc[i][c]=0.f;
  for(int k=0;k<DD;k+=4){
    float wv[4][8];
    #pragma unroll
    for(int r=0;r<4;r++){
      float4 lo=*(const float4*)&Wg1[(size_t)(k+r)*DD+tx*8];
      float4 hi=*(const float4*)&Wg1[(size_t)(k+r)*DD+tx*8+4];
      wv[r][0]=lo.x; wv[r][1]=lo.y; wv[r][2]=lo.z; wv[r][3]=lo.w;
      wv[r][4]=hi.x; wv[r][5]=hi.y; wv[r][6]=hi.z; wv[r][7]=hi.w;
    }
    #pragma unroll
    for(int i=0;i<6;i++){
      float4 a=*(const float4*)&Al[ty+16*i][k];
      #pragma unroll
      for(int c=0;c<8;c++)
        acc[i][c]+=a.x*wv[0][c]+a.y*wv[1][c]+a.z*wv[2][c]+a.w*wv[3][c];
    }
  }
  #pragma unroll
  for(int i=0;i<6;i++){
    int r=row0+ty+16*i;
    if(r<NN){
      float4 q0; q0.x=acc[i][0]; q0.y=acc[i][1]; q0.z=acc[i][2]; q0.w=acc[i][3];
      float4 q1; q1.x=acc[i][4]; q1.y=acc[i][5]; q1.z=acc[i][6]; q1.w=acc[i][7];
      *(float4*)&xw1[(size_t)r*DD+tx*8]=q0;
      *(float4*)&xw1[(size_t)r*DD+tx*8+4]=q1;
    }
  }
}

// ============ fp32 GEMM: 96x128 tile, 6x8 per thread (3 blocks/CU) ============
// ROWLIST: rows gathered from rlist[0..KSEL), outputs scattered to those rows.
template<int IN_SIG,int ACT,int OUT_BF16,int FUSE_SCORE,int ROWLIST>
__global__ __launch_bounds__(256) void k_gemm96(const float* __restrict__ A,
    const float* __restrict__ W, const float* __restrict__ bias,
    float* __restrict__ outf, ushort16* __restrict__ outb,
    const float* __restrict__ aparam, const float* __restrict__ hp,
    const float* __restrict__ bbil, float* __restrict__ score,
    const int* __restrict__ rlist){
  __shared__ float Al[96][132];
  int tid=threadIdx.x;
  int row0=blockIdx.x*96;
  {
    #pragma unroll
    for(int i=0;i<12;i++){
      int idx=i*256+tid;
      int r=idx>>5, c=(idx&31)*4;
      int gr; bool ok;
      if(ROWLIST){ int ri=row0+r; ok=(ri<KSEL); gr=ok?rlist[ri]:0; }
      else { gr=row0+r; ok=(gr<NN); }
      float4 v=make_float4(0.f,0.f,0.f,0.f);
      if(ok) v=*(const float4*)&A[(size_t)gr*DD+c];
      if(IN_SIG){ v.x=sigmoidf(v.x); v.y=sigmoidf(v.y); v.z=sigmoidf(v.z); v.w=sigmoidf(v.w); }
      *(float4*)&Al[r][c]=v;
    }
  }
  __syncthreads();
  int tx=tid&15, ty=tid>>4;
  float acc[6][8];
  #pragma unroll
  for(int i=0;i<6;i++)
    #pragma unroll
    for(int c=0;c<8;c++) acc[i][c]=0.f;

  for(int k=0;k<DD;k+=4){
    float wv[4][8];
    #pragma unroll
    for(int r=0;r<4;r++){
      float4 lo=*(const float4*)&W[(size_t)(k+r)*DD+tx*8];
      float4 hi=*(const float4*)&W[(size_t)(k+r)*DD+tx*8+4];
      wv[r][0]=lo.x; wv[r][1]=lo.y; wv[r][2]=lo.z; wv[r][3]=lo.w;
      wv[r][4]=hi.x; wv[r][5]=hi.y; wv[r][6]=hi.z; wv[r][7]=hi.w;
    }
    #pragma unroll
    for(int i=0;i<6;i++){
      float4 a=*(const float4*)&Al[ty+16*i][k];
      #pragma unroll
      for(int c=0;c<8;c++)
        acc[i][c]+=a.x*wv[0][c]+a.y*wv[1][c]+a.z*wv[2][c]+a.w*wv[3][c];
    }
  }

  if(FUSE_SCORE){
    float bb=bbil[0];
    #pragma unroll
    for(int i=0;i<6;i++){
      int r=row0+ty+16*i;
      float p=0.f;
      if(r<NN){
        float4 h0=*(const float4*)&hp[(size_t)r*DD+tx*8];
        float4 h1=*(const float4*)&hp[(size_t)r*DD+tx*8+4];
        p=acc[i][0]*h0.x+acc[i][1]*h0.y+acc[i][2]*h0.z+acc[i][3]*h0.w
         +acc[i][4]*h1.x+acc[i][5]*h1.y+acc[i][6]*h1.z+acc[i][7]*h1.w;
      }
      p+=__shfl_xor(p,1,64); p+=__shfl_xor(p,2,64);
      p+=__shfl_xor(p,4,64); p+=__shfl_xor(p,8,64);
      if(tx==0 && r<NN) score[r]=sigmoidf(p+bb);
    }
    return;
  }
  float bl[8]={0,0,0,0,0,0,0,0};
  if(bias){
    float4 b0=*(const float4*)&bias[tx*8];
    float4 b1=*(const float4*)&bias[tx*8+4];
    bl[0]=b0.x; bl[1]=b0.y; bl[2]=b0.z; bl[3]=b0.w;
    bl[4]=b1.x; bl[5]=b1.y; bl[6]=b1.z; bl[7]=b1.w;
  }
  float ap=ACT?aparam[0]:0.f;
  #pragma unroll
  for(int i=0;i<6;i++){
    int ri=row0+ty+16*i;
    int r; bool ok;
    if(ROWLIST){ ok=(ri<KSEL); r=ok?rlist[ri]:0; }
    else { r=ri; ok=(r<NN); }
    if(ok){
      float o[8];
      #pragma unroll
      for(int c=0;c<8;c++){
        float t=acc[i][c]+bl[c];
        if(ACT) t=t>=0.f?t:ap*t;
        o[c]=t;
      }
      if(OUT_BF16){
        uint4 pk;
        pk.x=((uint32)f2b(o[1])<<16)|f2b(o[0]);
        pk.y=((uint32)f2b(o[3])<<16)|f2b(o[2]);
        pk.z=((uint32)f2b(o[5])<<16)|f2b(o[4]);
        pk.w=((uint32)f2b(o[7])<<16)|f2b(o[6]);
        *(uint4*)&outb[(size_t)r*DD+tx*8]=pk;
      } else {
        float4 q0; q0.x=o[0]; q0.y=o[1]; q0.z=o[2]; q0.w=o[3];
        float4 q1; q1.x=o[4]; q1.y=o[5]; q1.z=o[6]; q1.w=o[7];
        *(float4*)&outf[(size_t)r*DD+tx*8]=q0;
        *(float4*)&outf[(size_t)r*DD+tx*8+4]=q1;
      }
    }
  }
}

// ---------- fp32 GCN aggregation, column-split halves (64 cols/pass) --------
// blockIdx < AB: cols 0..63 ; else cols 64..127. 4 groups x 16 lanes,
// 4 edges per wave-instruction, 16-edge unroll for MLP.
__global__ __launch_bounds__(256) void k_agg_f32h(const float* __restrict__ xw,
    const int* __restrict__ row_start, const int* __restrict__ csr,
    const float* __restrict__ inv, const float* __restrict__ bias,
    float* __restrict__ outp){
  int bid=blockIdx.x;
  int half=(bid>=AB)?1:0;
  int node=(bid-half*AB)*4+(threadIdx.x>>6);
  if(node>=NN) return;
  int lane=threadIdx.x&63;
  int g=lane>>4, li=lane&15;
  int colbase=half*64;
  const float* xwc=xw+colbase;
  int rs=row_start[node], re=row_start[node+1];
  float a0=0.f,a1=0.f,a2=0.f,a3=0.f;
  int j=rs;
  for(; j+15<re; j+=16){
    int s0=csr[j+g], s1=csr[j+4+g], s2=csr[j+8+g], s3=csr[j+12+g];
    float w0=inv[s0], w1=inv[s1], w2=inv[s2], w3=inv[s3];
    float4 v0=*(const float4*)&xwc[(size_t)s0*DD+li*4];
    float4 v1=*(const float4*)&xwc[(size_t)s1*DD+li*4];
    float4 v2=*(const float4*)&xwc[(size_t)s2*DD+li*4];
    float4 v3=*(const float4*)&xwc[(size_t)s3*DD+li*4];
    a0+=v0.x*w0+v1.x*w1+v2.x*w2+v3.x*w3;
    a1+=v0.y*w0+v1.y*w1+v2.y*w2+v3.y*w3;
    a2+=v0.z*w0+v1.z*w1+v2.z*w2+v3.z*w3;
    a3+=v0.w*w0+v1.w*w1+v2.w*w2+v3.w*w3;
  }
  for(; j+3<re; j+=4){
    int s=csr[j+g];
    float w=inv[s];
    float4 v=*(const float4*)&xwc[(size_t)s*DD+li*4];
    a0+=v.x*w; a1+=v.y*w; a2+=v.z*w; a3+=v.w*w;
  }
  int rem=re-j;
  if(g<rem){
    int s=csr[j+g];
    float w=inv[s];
    float4 v=*(const float4*)&xwc[(size_t)s*DD+li*4];
    a0+=v.x*w; a1+=v.y*w; a2+=v.z*w; a3+=v.w*w;
  }
  if(g==0){
    float wd=inv[node];
    float4 v=*(const float4*)&xwc[(size_t)node*DD+li*4];
    a0+=v.x*wd; a1+=v.y*wd; a2+=v.z*wd; a3+=v.w*wd;
  }
  a0+=__shfl_xor(a0,16,64); a0+=__shfl_xor(a0,32,64);
  a1+=__shfl_xor(a1,16,64); a1+=__shfl_xor(a1,32,64);
  a2+=__shfl_xor(a2,16,64); a2+=__shfl_xor(a2,32,64);
  a3+=__shfl_xor(a3,16,64); a3+=__shfl_xor(a3,32,64);
  if(g==0){
    float wn=inv[node];
    float4 bv=*(const float4*)&bias[colbase+li*4];
    float4 o;
    o.x=a0*wn+bv.x; o.y=a1*wn+bv.y; o.z=a2*wn+bv.z; o.w=a3*wn+bv.w;
    *(float4*)&outp[(size_t)node*DD+colbase+li*4]=o;
  }
}

// ---------------- bf16 GCN aggregation: 4 edges per dwordx4 --------------
// MODE 1: node = list[i] (all selected): out = (agg+bias)*score
// MODE 2: out = agg(skip !sel[s]) + bias + addbuf
template<int MODE>
__global__ __launch_bounds__(256) void k_agg_b16(const uint32* __restrict__ xwb,
    const int* __restrict__ row_start, const int* __restrict__ csr,
    const float* __restrict__ inv, const float* __restrict__ bias,
    float* __restrict__ outp, const float* __restrict__ score,
    const unsigned char* __restrict__ sel, const float* __restrict__ addbuf,
    const int* __restrict__ list){
  int idx4=blockIdx.x*4+(threadIdx.x>>6);
  int node;
  if(MODE==1){ if(idx4>=KSEL) return; node=list[idx4]; }
  else { node=idx4; if(node>=NN) return; }
  int lane=threadIdx.x&63;
  int g=lane>>4, li=lane&15;
  int rs=row_start[node], re=row_start[node+1];
  float a[8];
  #pragma unroll
  for(int c=0;c<8;c++) a[c]=0.f;
  int j=rs;
  for(; j+7<re; j+=8){
    int sA=csr[j+g], sB=csr[j+4+g];
    if(MODE!=2 || sel[sA]){
      float w=inv[sA];
      uint4 u=*(const uint4*)(xwb+(size_t)sA*64+li*4);
      addbf2(a[0],a[1],u.x,w); addbf2(a[2],a[3],u.y,w);
      addbf2(a[4],a[5],u.z,w); addbf2(a[6],a[7],u.w,w);
    }
    if(MODE!=2 || sel[sB]){
      float w=inv[sB];
      uint4 u=*(const uint4*)(xwb+(size_t)sB*64+li*4);
      addbf2(a[0],a[1],u.x,w); addbf2(a[2],a[3],u.y,w);
      addbf2(a[4],a[5],u.z,w); addbf2(a[6],a[7],u.w,w);
    }
  }
  for(; j+3<re; j+=4){
    int s=csr[j+g];
    if(MODE!=2 || sel[s]){
      float w=inv[s];
      uint4 u=*(const uint4*)(xwb+(size_t)s*64+li*4);
      addbf2(a[0],a[1],u.x,w); addbf2(a[2],a[3],u.y,w);
      addbf2(a[4],a[5],u.z,w); addbf2(a[6],a[7],u.w,w);
    }
  }
  int rem=re-j;
  if(g<rem){
    int s=csr[j+g];
    if(MODE!=2 || sel[s]){
      float w=inv[s];
      uint4 u=*(const uint4*)(xwb+(size_t)s*64+li*4);
      addbf2(a[0],a[1],u.x,w); addbf2(a[2],a[3],u.y,w);
      addbf2(a[4],a[5],u.z,w); addbf2(a[6],a[7],u.w,w);
    }
  }
  if(g==0 && (MODE!=2 || sel[node])){
    float wd=inv[node];
    uint4 u=*(const uint4*)(xwb+(size_t)node*64+li*4);
    addbf2(a[0],a[1],u.x,wd); addbf2(a[2],a[3],u.y,wd);
    addbf2(a[4],a[5],u.z,wd); addbf2(a[6],a[7],u.w,wd);
  }
  #pragma unroll
  for(int c=0;c<8;c++){
    a[c]+=__shfl_xor(a[c],16,64);
    a[c]+=__shfl_xor(a[c],32,64);
  }
  if(g<2){
    float wn=inv[node];
    int cb=li*8+g*4;
    float4 bv=*(const float4*)&bias[cb];
    float r0=a[g*4+0]*wn+bv.x, r1=a[g*4+1]*wn+bv.y;
    float r2=a[g*4+2]*wn+bv.z, r3=a[g*4+3]*wn+bv.w;
    if(MODE==1){
      float sc=score[node];
      r0*=sc; r1*=sc; r2*=sc; r3*=sc;
    } else {
      float4 ad=*(const float4*)&addbuf[(size_t)node*DD+cb];
      r0+=ad.x; r1+=ad.y; r2+=ad.z; r3+=ad.w;
    }
    float4 o; o.x=r0; o.y=r1; o.z=r2; o.w=r3;
    *(float4*)&outp[(size_t)node*DD+cb]=o;
  }
}

// ---------------- 3-pass radix select, LDS-privatized (multi-block) ----------
template<int NB,int PASS>
__global__ __launch_bounds__(256) void k_hist(const float* __restrict__ score,
    int* __restrict__ ghist, const int* __restrict__ ctrl){
  __shared__ int lh[NB];
  int tid=threadIdx.x;
  for(int i=tid;i<NB;i+=256) lh[i]=0;
  __syncthreads();
  int p0=0,p01=0;
  if(PASS==1) p0=ctrl[0];
  if(PASS==2) p01=ctrl[2];
  for(int i=blockIdx.x*256+tid; i<NN; i+=gridDim.x*256){
    unsigned b=__float_as_uint(score[i]);
    if(PASS==0) atomicAdd(&lh[b>>20],1);
    else if(PASS==1){ if((int)(b>>20)==p0) atomicAdd(&lh[(b>>8)&0xFFF],1); }
    else { if((int)(b>>8)==p01) atomicAdd(&lh[b&0xFF],1); }
  }
  __syncthreads();
  for(int i=tid;i<NB;i+=256){ int v=lh[i]; if(v) atomicAdd(&ghist[i],v); }
}

template<int NB,int PASS>
__global__ void k_findb(const int* __restrict__ hist, int* __restrict__ ctrl){
  const int NT=NB/4;
  __shared__ int gsum[NT];
  int t=threadIdx.x;
  int s=hist[t*4]+hist[t*4+1]+hist[t*4+2]+hist[t*4+3];
  int x=s; gsum[t]=x; __syncthreads();
  for(int off=1;off<NT;off<<=1){
    int y=(t+off<NT)?gsum[t+off]:0;
    __syncthreads();
    x+=y; gsum[t]=x; __syncthreads();
  }
  int base;
  if(PASS==0) base=0; else if(PASS==1) base=ctrl[1]; else base=ctrl[3];
  int above=base+((t<NT-1)?gsum[t+1]:0);
  int incl=base+gsum[t];
  if(above<KSEL && incl>=KSEL){
    int c=above, B=0;
    for(int b=3;b>=0;b--){
      int hb=hist[t*4+b];
      if(c+hb>=KSEL){ B=t*4+b; break; }
      c+=hb;
    }
    if(PASS==0){ ctrl[0]=B; ctrl[1]=c; }
    else if(PASS==1){ ctrl[2]=(ctrl[0]<<12)|B; ctrl[3]=c; }
    else { ctrl[4]=(int)((((unsigned)ctrl[2])<<8)|(unsigned)B); ctrl[5]=KSEL-c; }
  }
}

// mark + compacted list build
__global__ void k_sel(const float* __restrict__ score, int* __restrict__ ctrl,
                      int* __restrict__ tie_list, unsigned char* __restrict__ sel,
                      int* __restrict__ list){
  int i=blockIdx.x*256+threadIdx.x;
  if(i>=NN) return;
  unsigned b=__float_as_uint(score[i]);
  unsigned thr=(unsigned)ctrl[4];
  if(b>thr){
    sel[i]=1;
    int p=atomicAdd(&ctrl[7],1);
    list[p]=i;
  }
  else if(b==thr){
    sel[i]=0;
    int p=atomicAdd(&ctrl[6],1);
    if(p<4096) tie_list[p]=i;
  } else sel[i]=0;
}

__global__ __launch_bounds__(256) void k_tie(const int* __restrict__ ctrl_c,
    int* __restrict__ ctrl, const int* __restrict__ tie_list,
    unsigned char* __restrict__ sel, int* __restrict__ list){
  int m=ctrl_c[6]; if(m>4096) m=4096;
  int needed=ctrl_c[5];
  for(int t=threadIdx.x; t<m; t+=blockDim.x){
    int idx=tie_list[t];
    int rank=0;
    for(int j=0;j<m;j++) rank+=(tie_list[j]<idx)?1:0;
    if(rank<needed){
      sel[idx]=1;
      int p=atomicAdd(&ctrl[7],1);
      list[p]=idx;
    }
  }
}

// ============================================================================
extern "C" void kernel_launch(void* const* d_in, const int* in_sizes, int n_in,
                              void* d_out, int out_size, void* d_ws, size_t ws_size,
                              hipStream_t stream){
  const float* feat   =(const float*)d_in[0];
  const int*   ei     =(const int*)  d_in[2];
  const int*   src    = ei;
  const int*   dst    = ei + NE;
  const float* Wd     =(const float*)d_in[3];
  const float* bd     =(const float*)d_in[4];
  const float* prelu_a=(const float*)d_in[5];
  const float* Wbil   =(const float*)d_in[6];
  const float* bbil   =(const float*)d_in[7];
  const float* Wg1    =(const float*)d_in[8];
  const float* bg1    =(const float*)d_in[9];
  const float* Wg2    =(const float*)d_in[10];
  const float* bg2    =(const float*)d_in[11];
  const float* Wg3    =(const float*)d_in[12];
  const float* bg3    =(const float*)d_in[13];
  float* out=(float*)d_out;

  char* p=(char*)d_ws;
  auto alloc=[&](size_t bytes)->void*{ void* r=(void*)p; p+=((bytes+255)/256)*256; return r; };
  float* h_pos   =(float*)alloc((size_t)NN*DD*4);
  float* embed   =(float*)alloc((size_t)NN*DD*4);
  float* xw      =(float*)alloc((size_t)NN*DD*4);   // fp32 xw1 / bf16 xw2,xw3 / pairs (early)
  float* score   =(float*)alloc((size_t)NN*4);
  float* inv_sq  =(float*)alloc((size_t)NN*4);
  float* WbT     =(float*)alloc((size_t)DD*DD*4);
  int*   row_st  =(int*)  alloc((size_t)(NN+1)*4);
  int*   csr_src =(int*)  alloc((size_t)NE*4);
  int*   ctrl    =(int*)  alloc(64);                // contiguous zero-span start
  int*   hist0   =(int*)  alloc(4096*4);
  int*   hist1   =(int*)  alloc(4096*4);
  int*   hist2   =(int*)  alloc(256*4);
  int*   tie_list=(int*)  alloc(4096*4);
  int*   list    =(int*)  alloc((size_t)KSEL*4);
  unsigned char* sel=(unsigned char*)alloc(NN);
  int*   btot    =(int*)  alloc((size_t)NBK*4);
  int*   boff    =(int*)  alloc((size_t)(NBK+1)*4);
  int*   blkcnt  =(int*)  alloc((size_t)NBLKA*NBK*4);
  int*   blkbase =(int*)  alloc((size_t)NBLKA*NBK*4);
  uint32* pairs  =(uint32*)xw;                      // aliased: lifetime before xw1
  ushort16* xwb  =(ushort16*)xw;
  float* fine = out;

  const int NB=(NN+255)/256;
  const int GB=(NN+95)/96;       // 521 gemm blocks
  const int GBL=(KSEL+95)/96;    // 261 compacted gemm blocks
  const int ABL=(KSEL+3)/4;      // 6250 compacted agg blocks

  // prep: transpose Wbil + zero ctrl/hist0/hist1/hist2 (8512 ints incl padding) + btot
  k_prep<<<64,256,0,stream>>>(Wbil, WbT, ctrl, btot);

  // graph structure: bucketed counting sort -> CSR + degrees + inv_sqrt
  k_bcount  <<<NBLKA,1024,0,stream>>>(dst, btot, blkcnt);
  k_bscan   <<<1,512,0,stream>>>(btot, boff, blkcnt, blkbase, row_st);
  k_bscatter<<<NBLKA,1024,0,stream>>>(src, dst, blkbase, pairs);
  k_bfinal  <<<NBK,256,0,stream>>>(pairs, boff, row_st, inv_sq, csr_src);

  // h_pos = prelu(feat@Wd+bd) ; xw1 = h_pos@Wg1    [fused dual GEMM]
  k_gemm_dual<<<GB,256,0,stream>>>(feat, Wd, bd, prelu_a, Wg1, h_pos, xw);
  // embed = gcn1 aggregation (column-split halves)
  k_agg_f32h<<<2*AB,256,0,stream>>>(xw, row_st, csr_src, inv_sq, bg1, embed);
  // score = sigmoid(rowdot(h_pos, sigmoid(embed)@Wbil^T) + bbil)   [fused]
  k_gemm96<1,0,0,1,0><<<GB,256,0,stream>>>(embed, WbT, nullptr, nullptr, nullptr, nullptr, h_pos, bbil, score, nullptr);
  // top-k: 3-pass LDS-privatized radix select (multi-block) + compacted list
  k_hist<4096,0><<<64,256,0,stream>>>(score, hist0, ctrl);
  k_findb<4096,0><<<1,1024,0,stream>>>(hist0, ctrl);
  k_hist<4096,1><<<64,256,0,stream>>>(score, hist1, ctrl);
  k_findb<4096,1><<<1,1024,0,stream>>>(hist1, ctrl);
  k_hist<256,2><<<64,256,0,stream>>>(score, hist2, ctrl);
  k_findb<256,2><<<1,64,0,stream>>>(hist2, ctrl);
  k_sel<<<NB,256,0,stream>>>(score, ctrl, tie_list, sel, list);
  k_tie<<<1,256,0,stream>>>(ctrl, ctrl, tie_list, sel, list);
  // fine[list] = (gcn2(embed)+bg2)[list] * score[list]   (bf16 xw2, compacted nodes)
  k_gemm96<0,0,1,0,0><<<GB,256,0,stream>>>(embed, Wg2, nullptr, nullptr, xwb, nullptr, nullptr, nullptr, nullptr, nullptr);
  k_agg_b16<1><<<ABL,256,0,stream>>>((const uint32*)xwb, row_st, csr_src, inv_sq, bg2, fine, score, sel, nullptr, list);
  // out = gcn3(fine) + embed   (bf16 xw3 over selected rows only; MODE2 skips !sel sources)
  k_gemm96<0,0,1,0,1><<<GBL,256,0,stream>>>(fine, Wg3, nullptr, nullptr, xwb, nullptr, nullptr, nullptr, nullptr, list);
  k_agg_b16<2><<<2*AB/2,256,0,stream>>>((const uint32*)xwb, row_st, csr_src, inv_sq, bg3, out, nullptr, sel, embed, nullptr);
}

// Round 11
// 375.904 us; speedup vs baseline: 1.0013x; 1.0013x over previous
//
#include <hip/hip_runtime.h>
#include <hip/hip_bf16.h>

#define NN 50000
#define NE 800000
#define DD 128
#define KSEL 25000
#define NBK 391                 // buckets of 128 nodes (graph build)
#define NBLKA 98                // (NE+8191)/8192
#define AB 12500                // agg node-blocks (4 nodes/block)

typedef unsigned int uint32;
typedef unsigned short ushort16;

__device__ __forceinline__ float sigmoidf(float x){ return 1.f/(1.f+__expf(-x)); }

__device__ __forceinline__ unsigned short f2b(float f){
  union{float f; unsigned u;} v; v.f=f;
  unsigned r=(v.u + 0x7fffu + ((v.u>>16)&1u))>>16;
  return (unsigned short)r;
}

__device__ __forceinline__ void addbf2(float&lo,float&hi,uint32 u,float w){
  lo+=__uint_as_float(u<<16)*w;
  hi+=__uint_as_float(u&0xffff0000u)*w;
}

// ============ prep: transpose Wbil + zero ctrl/hists/btot (1 dispatch) ======
__global__ __launch_bounds__(256) void k_prep(const float* __restrict__ W,
    float* __restrict__ Wt, int* __restrict__ zspan, int* __restrict__ btot){
  int i=blockIdx.x*256+threadIdx.x;      // 64 blocks -> 16384 threads
  if(i<DD*DD) Wt[i]=W[(i&127)*DD+(i>>7)];
  if(i<8512) zspan[i]=0;                 // ctrl(256B)+hist0+hist1+hist2
  if(i<NBK) btot[i]=0;
}

// ================= graph build: bucketed counting sort =================
__global__ __launch_bounds__(1024) void k_bcount(const int* __restrict__ dst,
    int* __restrict__ btot, int* __restrict__ blkcnt){
  __shared__ int h[NBK];
  int tid=threadIdx.x;
  for(int i=tid;i<NBK;i+=1024) h[i]=0;
  __syncthreads();
  int e0=blockIdx.x*8192;
  #pragma unroll
  for(int t=0;t<8;t++){
    int e=e0+t*1024+tid;
    if(e<NE) atomicAdd(&h[dst[e]>>7],1);
  }
  __syncthreads();
  for(int i=tid;i<NBK;i+=1024){
    int c=h[i];
    blkcnt[blockIdx.x*NBK+i]=c;
    if(c) atomicAdd(&btot[i],c);
  }
}

__global__ __launch_bounds__(512) void k_bscan(const int* __restrict__ btot,
    int* __restrict__ boff, const int* __restrict__ blkcnt, int* __restrict__ blkbase,
    int* __restrict__ row_start){
  __shared__ int sdata[512];
  int tid=threadIdx.x;
  int v=(tid<NBK)?btot[tid]:0;
  sdata[tid]=v; __syncthreads();
  for(int off=1;off<512;off<<=1){
    int y=(tid>=off)?sdata[tid-off]:0;
    __syncthreads();
    sdata[tid]+=y;
    __syncthreads();
  }
  int excl=sdata[tid]-v;
  if(tid<NBK) boff[tid]=excl;
  if(tid==NBK-1){ boff[NBK]=excl+v; row_start[NN]=NE; }
  if(tid<NBK){
    int run=excl;
    for(int b=0;b<NBLKA;b++){
      int c=blkcnt[b*NBK+tid];
      blkbase[b*NBK+tid]=run;
      run+=c;
    }
  }
}

// pack: src (17 bits) | local-dst (7 bits) << 17
__global__ __launch_bounds__(1024) void k_bscatter(const int* __restrict__ src,
    const int* __restrict__ dst, const int* __restrict__ blkbase, uint32* __restrict__ pairs){
  __shared__ int cur[NBK];
  int tid=threadIdx.x;
  for(int i=tid;i<NBK;i+=1024) cur[i]=blkbase[blockIdx.x*NBK+i];
  __syncthreads();
  int e0=blockIdx.x*8192;
  #pragma unroll
  for(int t=0;t<8;t++){
    int e=e0+t*1024+tid;
    if(e<NE){
      int d=dst[e];
      int p=atomicAdd(&cur[d>>7],1);
      pairs[p]=(unsigned)src[e] | ((unsigned)(d&127)<<17);
    }
  }
}

__global__ __launch_bounds__(256) void k_bfinal(const uint32* __restrict__ pairs,
    const int* __restrict__ boff, int* __restrict__ row_start,
    float* __restrict__ inv_sq, int* __restrict__ csr_src){
  __shared__ int degl[128];
  __shared__ int cur[128];
  __shared__ int ssum[2];
  int b=blockIdx.x, tid=threadIdx.x;
  int lo=boff[b], hi=boff[b+1];
  if(tid<128) degl[tid]=0;
  __syncthreads();
  for(int e=lo+tid;e<hi;e+=256) atomicAdd(&degl[pairs[e]>>17],1);
  __syncthreads();
  int v=0,x=0;
  if(tid<128){
    v=degl[tid]; x=v;
    #pragma unroll
    for(int off=1;off<64;off<<=1){
      int y=__shfl_up(x,off,64);
      if((tid&63)>=off) x+=y;
    }
    if((tid&63)==63) ssum[tid>>6]=x;
  }
  __syncthreads();
  if(tid<128){
    int incl=x+((tid>=64)?ssum[0]:0);
    int node=b*128+tid;
    int excl=lo+incl-v;
    if(node<NN){
      row_start[node]=excl;
      cur[tid]=excl;
      inv_sq[node]=1.f/sqrtf((float)(v+1));
    }
  }
  __syncthreads();
  for(int e=lo+tid;e<hi;e+=256){
    uint32 u=pairs[e];
    int p=atomicAdd(&cur[u>>17],1);
    csr_src[p]=(int)(u&0x1FFFFu);
  }
}

// ============ fp32 GEMM: 64x128 tile, 4x8 per thread (4 blocks/CU) ============
// ROWLIST: rows gathered from rlist[0..KSEL), outputs scattered to those rows.
template<int IN_SIG,int ACT,int OUT_BF16,int FUSE_SCORE,int ROWLIST>
__global__ __launch_bounds__(256) void k_gemm64t(const float* __restrict__ A,
    const float* __restrict__ W, const float* __restrict__ bias,
    float* __restrict__ outf, ushort16* __restrict__ outb,
    const float* __restrict__ aparam, const float* __restrict__ hp,
    const float* __restrict__ bbil, float* __restrict__ score,
    const int* __restrict__ rlist){
  __shared__ float Al[64][132];           // 33.8 KB -> 4 blocks/CU
  int tid=threadIdx.x;
  int row0=blockIdx.x*64;
  {
    #pragma unroll
    for(int i=0;i<8;i++){
      int idx=i*256+tid;                  // 0..2047
      int r=idx>>5, c=(idx&31)*4;
      int gr; bool ok;
      if(ROWLIST){ int ri=row0+r; ok=(ri<KSEL); gr=ok?rlist[ri]:0; }
      else { gr=row0+r; ok=(gr<NN); }
      float4 v=make_float4(0.f,0.f,0.f,0.f);
      if(ok) v=*(const float4*)&A[(size_t)gr*DD+c];
      if(IN_SIG){ v.x=sigmoidf(v.x); v.y=sigmoidf(v.y); v.z=sigmoidf(v.z); v.w=sigmoidf(v.w); }
      *(float4*)&Al[r][c]=v;
    }
  }
  __syncthreads();
  int tx=tid&15, ty=tid>>4;               // cols tx*8..+7 ; rows ty+16*i (i<4)
  float acc[4][8];
  #pragma unroll
  for(int i=0;i<4;i++)
    #pragma unroll
    for(int c=0;c<8;c++) acc[i][c]=0.f;

  for(int k=0;k<DD;k+=4){
    float wv[4][8];
    #pragma unroll
    for(int r=0;r<4;r++){
      float4 lo=*(const float4*)&W[(size_t)(k+r)*DD+tx*8];
      float4 hi=*(const float4*)&W[(size_t)(k+r)*DD+tx*8+4];
      wv[r][0]=lo.x; wv[r][1]=lo.y; wv[r][2]=lo.z; wv[r][3]=lo.w;
      wv[r][4]=hi.x; wv[r][5]=hi.y; wv[r][6]=hi.z; wv[r][7]=hi.w;
    }
    #pragma unroll
    for(int i=0;i<4;i++){
      float4 a=*(const float4*)&Al[ty+16*i][k];
      #pragma unroll
      for(int c=0;c<8;c++)
        acc[i][c]+=a.x*wv[0][c]+a.y*wv[1][c]+a.z*wv[2][c]+a.w*wv[3][c];
    }
  }

  if(FUSE_SCORE){
    float bb=bbil[0];
    #pragma unroll
    for(int i=0;i<4;i++){
      int r=row0+ty+16*i;
      float p=0.f;
      if(r<NN){
        float4 h0=*(const float4*)&hp[(size_t)r*DD+tx*8];
        float4 h1=*(const float4*)&hp[(size_t)r*DD+tx*8+4];
        p=acc[i][0]*h0.x+acc[i][1]*h0.y+acc[i][2]*h0.z+acc[i][3]*h0.w
         +acc[i][4]*h1.x+acc[i][5]*h1.y+acc[i][6]*h1.z+acc[i][7]*h1.w;
      }
      p+=__shfl_xor(p,1,64); p+=__shfl_xor(p,2,64);
      p+=__shfl_xor(p,4,64); p+=__shfl_xor(p,8,64);
      if(tx==0 && r<NN) score[r]=sigmoidf(p+bb);
    }
    return;
  }
  float bl[8]={0,0,0,0,0,0,0,0};
  if(bias){
    float4 b0=*(const float4*)&bias[tx*8];
    float4 b1=*(const float4*)&bias[tx*8+4];
    bl[0]=b0.x; bl[1]=b0.y; bl[2]=b0.z; bl[3]=b0.w;
    bl[4]=b1.x; bl[5]=b1.y; bl[6]=b1.z; bl[7]=b1.w;
  }
  float ap=ACT?aparam[0]:0.f;
  #pragma unroll
  for(int i=0;i<4;i++){
    int ri=row0+ty+16*i;
    int r; bool ok;
    if(ROWLIST){ ok=(ri<KSEL); r=ok?rlist[ri]:0; }
    else { r=ri; ok=(r<NN); }
    if(ok){
      float o[8];
      #pragma unroll
      for(int c=0;c<8;c++){
        float t=acc[i][c]+bl[c];
        if(ACT) t=t>=0.f?t:ap*t;
        o[c]=t;
      }
      if(OUT_BF16){
        uint4 pk;
        pk.x=((uint32)f2b(o[1])<<16)|f2b(o[0]);
        pk.y=((uint32)f2b(o[3])<<16)|f2b(o[2]);
        pk.z=((uint32)f2b(o[5])<<16)|f2b(o[4]);
        pk.w=((uint32)f2b(o[7])<<16)|f2b(o[6]);
        *(uint4*)&outb[(size_t)r*DD+tx*8]=pk;
      } else {
        float4 q0; q0.x=o[0]; q0.y=o[1]; q0.z=o[2]; q0.w=o[3];
        float4 q1; q1.x=o[4]; q1.y=o[5]; q1.z=o[6]; q1.w=o[7];
        *(float4*)&outf[(size_t)r*DD+tx*8]=q0;
        *(float4*)&outf[(size_t)r*DD+tx*8+4]=q1;
      }
    }
  }
}

// ---------- fp32 GCN aggregation, column-split halves (64 cols/pass) --------
__global__ __launch_bounds__(256) void k_agg_f32h(const float* __restrict__ xw,
    const int* __restrict__ row_start, const int* __restrict__ csr,
    const float* __restrict__ inv, const float* __restrict__ bias,
    float* __restrict__ outp){
  int bid=blockIdx.x;
  int half=(bid>=AB)?1:0;
  int node=(bid-half*AB)*4+(threadIdx.x>>6);
  if(node>=NN) return;
  int lane=threadIdx.x&63;
  int g=lane>>4, li=lane&15;
  int colbase=half*64;
  const float* xwc=xw+colbase;
  int rs=row_start[node], re=row_start[node+1];
  float a0=0.f,a1=0.f,a2=0.f,a3=0.f;
  int j=rs;
  for(; j+15<re; j+=16){
    int s0=csr[j+g], s1=csr[j+4+g], s2=csr[j+8+g], s3=csr[j+12+g];
    float w0=inv[s0], w1=inv[s1], w2=inv[s2], w3=inv[s3];
    float4 v0=*(const float4*)&xwc[(size_t)s0*DD+li*4];
    float4 v1=*(const float4*)&xwc[(size_t)s1*DD+li*4];
    float4 v2=*(const float4*)&xwc[(size_t)s2*DD+li*4];
    float4 v3=*(const float4*)&xwc[(size_t)s3*DD+li*4];
    a0+=v0.x*w0+v1.x*w1+v2.x*w2+v3.x*w3;
    a1+=v0.y*w0+v1.y*w1+v2.y*w2+v3.y*w3;
    a2+=v0.z*w0+v1.z*w1+v2.z*w2+v3.z*w3;
    a3+=v0.w*w0+v1.w*w1+v2.w*w2+v3.w*w3;
  }
  for(; j+3<re; j+=4){
    int s=csr[j+g];
    float w=inv[s];
    float4 v=*(const float4*)&xwc[(size_t)s*DD+li*4];
    a0+=v.x*w; a1+=v.y*w; a2+=v.z*w; a3+=v.w*w;
  }
  int rem=re-j;
  if(g<rem){
    int s=csr[j+g];
    float w=inv[s];
    float4 v=*(const float4*)&xwc[(size_t)s*DD+li*4];
    a0+=v.x*w; a1+=v.y*w; a2+=v.z*w; a3+=v.w*w;
  }
  if(g==0){
    float wd=inv[node];
    float4 v=*(const float4*)&xwc[(size_t)node*DD+li*4];
    a0+=v.x*wd; a1+=v.y*wd; a2+=v.z*wd; a3+=v.w*wd;
  }
  a0+=__shfl_xor(a0,16,64); a0+=__shfl_xor(a0,32,64);
  a1+=__shfl_xor(a1,16,64); a1+=__shfl_xor(a1,32,64);
  a2+=__shfl_xor(a2,16,64); a2+=__shfl_xor(a2,32,64);
  a3+=__shfl_xor(a3,16,64); a3+=__shfl_xor(a3,32,64);
  if(g==0){
    float wn=inv[node];
    float4 bv=*(const float4*)&bias[colbase+li*4];
    float4 o;
    o.x=a0*wn+bv.x; o.y=a1*wn+bv.y; o.z=a2*wn+bv.z; o.w=a3*wn+bv.w;
    *(float4*)&outp[(size_t)node*DD+colbase+li*4]=o;
  }
}

// ---------------- bf16 GCN aggregation: 4 edges per dwordx4 --------------
// MODE 1: node = list[i] (all selected): out = (agg+bias)*score
// MODE 2: out = agg(skip !sel[s]) + bias + addbuf
template<int MODE>
__global__ __launch_bounds__(256) void k_agg_b16(const uint32* __restrict__ xwb,
    const int* __restrict__ row_start, const int* __restrict__ csr,
    const float* __restrict__ inv, const float* __restrict__ bias,
    float* __restrict__ outp, const float* __restrict__ score,
    const unsigned char* __restrict__ sel, const float* __restrict__ addbuf,
    const int* __restrict__ list){
  int idx4=blockIdx.x*4+(threadIdx.x>>6);
  int node;
  if(MODE==1){ if(idx4>=KSEL) return; node=list[idx4]; }
  else { node=idx4; if(node>=NN) return; }
  int lane=threadIdx.x&63;
  int g=lane>>4, li=lane&15;
  int rs=row_start[node], re=row_start[node+1];
  float a[8];
  #pragma unroll
  for(int c=0;c<8;c++) a[c]=0.f;
  int j=rs;
  for(; j+7<re; j+=8){
    int sA=csr[j+g], sB=csr[j+4+g];
    if(MODE!=2 || sel[sA]){
      float w=inv[sA];
      uint4 u=*(const uint4*)(xwb+(size_t)sA*64+li*4);
      addbf2(a[0],a[1],u.x,w); addbf2(a[2],a[3],u.y,w);
      addbf2(a[4],a[5],u.z,w); addbf2(a[6],a[7],u.w,w);
    }
    if(MODE!=2 || sel[sB]){
      float w=inv[sB];
      uint4 u=*(const uint4*)(xwb+(size_t)sB*64+li*4);
      addbf2(a[0],a[1],u.x,w); addbf2(a[2],a[3],u.y,w);
      addbf2(a[4],a[5],u.z,w); addbf2(a[6],a[7],u.w,w);
    }
  }
  for(; j+3<re; j+=4){
    int s=csr[j+g];
    if(MODE!=2 || sel[s]){
      float w=inv[s];
      uint4 u=*(const uint4*)(xwb+(size_t)s*64+li*4);
      addbf2(a[0],a[1],u.x,w); addbf2(a[2],a[3],u.y,w);
      addbf2(a[4],a[5],u.z,w); addbf2(a[6],a[7],u.w,w);
    }
  }
  int rem=re-j;
  if(g<rem){
    int s=csr[j+g];
    if(MODE!=2 || sel[s]){
      float w=inv[s];
      uint4 u=*(const uint4*)(xwb+(size_t)s*64+li*4);
      addbf2(a[0],a[1],u.x,w); addbf2(a[2],a[3],u.y,w);
      addbf2(a[4],a[5],u.z,w); addbf2(a[6],a[7],u.w,w);
    }
  }
  if(g==0 && (MODE!=2 || sel[node])){
    float wd=inv[node];
    uint4 u=*(const uint4*)(xwb+(size_t)node*64+li*4);
    addbf2(a[0],a[1],u.x,wd); addbf2(a[2],a[3],u.y,wd);
    addbf2(a[4],a[5],u.z,wd); addbf2(a[6],a[7],u.w,wd);
  }
  #pragma unroll
  for(int c=0;c<8;c++){
    a[c]+=__shfl_xor(a[c],16,64);
    a[c]+=__shfl_xor(a[c],32,64);
  }
  if(g<2){
    float wn=inv[node];
    int cb=li*8+g*4;
    float4 bv=*(const float4*)&bias[cb];
    float r0=a[g*4+0]*wn+bv.x, r1=a[g*4+1]*wn+bv.y;
    float r2=a[g*4+2]*wn+bv.z, r3=a[g*4+3]*wn+bv.w;
    if(MODE==1){
      float sc=score[node];
      r0*=sc; r1*=sc; r2*=sc; r3*=sc;
    } else {
      float4 ad=*(const float4*)&addbuf[(size_t)node*DD+cb];
      r0+=ad.x; r1+=ad.y; r2+=ad.z; r3+=ad.w;
    }
    float4 o; o.x=r0; o.y=r1; o.z=r2; o.w=r3;
    *(float4*)&outp[(size_t)node*DD+cb]=o;
  }
}

// ---------------- 3-pass radix select, LDS-privatized (multi-block) ----------
template<int NB,int PASS>
__global__ __launch_bounds__(256) void k_hist(const float* __restrict__ score,
    int* __restrict__ ghist, const int* __restrict__ ctrl){
  __shared__ int lh[NB];
  int tid=threadIdx.x;
  for(int i=tid;i<NB;i+=256) lh[i]=0;
  __syncthreads();
  int p0=0,p01=0;
  if(PASS==1) p0=ctrl[0];
  if(PASS==2) p01=ctrl[2];
  for(int i=blockIdx.x*256+tid; i<NN; i+=gridDim.x*256){
    unsigned b=__float_as_uint(score[i]);
    if(PASS==0) atomicAdd(&lh[b>>20],1);
    else if(PASS==1){ if((int)(b>>20)==p0) atomicAdd(&lh[(b>>8)&0xFFF],1); }
    else { if((int)(b>>8)==p01) atomicAdd(&lh[b&0xFF],1); }
  }
  __syncthreads();
  for(int i=tid;i<NB;i+=256){ int v=lh[i]; if(v) atomicAdd(&ghist[i],v); }
}

template<int NB,int PASS>
__global__ void k_findb(const int* __restrict__ hist, int* __restrict__ ctrl){
  const int NT=NB/4;
  __shared__ int gsum[NT];
  int t=threadIdx.x;
  int s=hist[t*4]+hist[t*4+1]+hist[t*4+2]+hist[t*4+3];
  int x=s; gsum[t]=x; __syncthreads();
  for(int off=1;off<NT;off<<=1){
    int y=(t+off<NT)?gsum[t+off]:0;
    __syncthreads();
    x+=y; gsum[t]=x; __syncthreads();
  }
  int base;
  if(PASS==0) base=0; else if(PASS==1) base=ctrl[1]; else base=ctrl[3];
  int above=base+((t<NT-1)?gsum[t+1]:0);
  int incl=base+gsum[t];
  if(above<KSEL && incl>=KSEL){
    int c=above, B=0;
    for(int b=3;b>=0;b--){
      int hb=hist[t*4+b];
      if(c+hb>=KSEL){ B=t*4+b; break; }
      c+=hb;
    }
    if(PASS==0){ ctrl[0]=B; ctrl[1]=c; }
    else if(PASS==1){ ctrl[2]=(ctrl[0]<<12)|B; ctrl[3]=c; }
    else { ctrl[4]=(int)((((unsigned)ctrl[2])<<8)|(unsigned)B); ctrl[5]=KSEL-c; }
  }
}

// mark + compacted list build
__global__ void k_sel(const float* __restrict__ score, int* __restrict__ ctrl,
                      int* __restrict__ tie_list, unsigned char* __restrict__ sel,
                      int* __restrict__ list){
  int i=blockIdx.x*256+threadIdx.x;
  if(i>=NN) return;
  unsigned b=__float_as_uint(score[i]);
  unsigned thr=(unsigned)ctrl[4];
  if(b>thr){
    sel[i]=1;
    int p=atomicAdd(&ctrl[7],1);
    list[p]=i;
  }
  else if(b==thr){
    sel[i]=0;
    int p=atomicAdd(&ctrl[6],1);
    if(p<4096) tie_list[p]=i;
  } else sel[i]=0;
}

__global__ __launch_bounds__(256) void k_tie(const int* __restrict__ ctrl_c,
    int* __restrict__ ctrl, const int* __restrict__ tie_list,
    unsigned char* __restrict__ sel, int* __restrict__ list){
  int m=ctrl_c[6]; if(m>4096) m=4096;
  int needed=ctrl_c[5];
  for(int t=threadIdx.x; t<m; t+=blockDim.x){
    int idx=tie_list[t];
    int rank=0;
    for(int j=0;j<m;j++) rank+=(tie_list[j]<idx)?1:0;
    if(rank<needed){
      sel[idx]=1;
      int p=atomicAdd(&ctrl[7],1);
      list[p]=idx;
    }
  }
}

// ============================================================================
extern "C" void kernel_launch(void* const* d_in, const int* in_sizes, int n_in,
                              void* d_out, int out_size, void* d_ws, size_t ws_size,
                              hipStream_t stream){
  const float* feat   =(const float*)d_in[0];
  const int*   ei     =(const int*)  d_in[2];
  const int*   src    = ei;
  const int*   dst    = ei + NE;
  const float* Wd     =(const float*)d_in[3];
  const float* bd     =(const float*)d_in[4];
  const float* prelu_a=(const float*)d_in[5];
  const float* Wbil   =(const float*)d_in[6];
  const float* bbil   =(const float*)d_in[7];
  const float* Wg1    =(const float*)d_in[8];
  const float* bg1    =(const float*)d_in[9];
  const float* Wg2    =(const float*)d_in[10];
  const float* bg2    =(const float*)d_in[11];
  const float* Wg3    =(const float*)d_in[12];
  const float* bg3    =(const float*)d_in[13];
  float* out=(float*)d_out;

  char* p=(char*)d_ws;
  auto alloc=[&](size_t bytes)->void*{ void* r=(void*)p; p+=((bytes+255)/256)*256; return r; };
  float* h_pos   =(float*)alloc((size_t)NN*DD*4);
  float* embed   =(float*)alloc((size_t)NN*DD*4);
  float* xw      =(float*)alloc((size_t)NN*DD*4);   // fp32 xw1 / bf16 xw2,xw3 / pairs (early)
  float* score   =(float*)alloc((size_t)NN*4);
  float* inv_sq  =(float*)alloc((size_t)NN*4);
  float* WbT     =(float*)alloc((size_t)DD*DD*4);
  int*   row_st  =(int*)  alloc((size_t)(NN+1)*4);
  int*   csr_src =(int*)  alloc((size_t)NE*4);
  int*   ctrl    =(int*)  alloc(64);                // contiguous zero-span start
  int*   hist0   =(int*)  alloc(4096*4);
  int*   hist1   =(int*)  alloc(4096*4);
  int*   hist2   =(int*)  alloc(256*4);
  int*   tie_list=(int*)  alloc(4096*4);
  int*   list    =(int*)  alloc((size_t)KSEL*4);
  unsigned char* sel=(unsigned char*)alloc(NN);
  int*   btot    =(int*)  alloc((size_t)NBK*4);
  int*   boff    =(int*)  alloc((size_t)(NBK+1)*4);
  int*   blkcnt  =(int*)  alloc((size_t)NBLKA*NBK*4);
  int*   blkbase =(int*)  alloc((size_t)NBLKA*NBK*4);
  uint32* pairs  =(uint32*)xw;                      // aliased: lifetime before xw1
  ushort16* xwb  =(ushort16*)xw;
  float* fine = out;

  const int NB=(NN+255)/256;
  const int GB=(NN+63)/64;       // 782 gemm blocks
  const int GBL=(KSEL+63)/64;    // 391 compacted gemm blocks
  const int ABL=(KSEL+3)/4;      // 6250 compacted agg blocks

  // prep: transpose Wbil + zero ctrl/hist0/hist1/hist2 + btot
  k_prep<<<64,256,0,stream>>>(Wbil, WbT, ctrl, btot);

  // graph structure: bucketed counting sort -> CSR + degrees + inv_sqrt
  k_bcount  <<<NBLKA,1024,0,stream>>>(dst, btot, blkcnt);
  k_bscan   <<<1,512,0,stream>>>(btot, boff, blkcnt, blkbase, row_st);
  k_bscatter<<<NBLKA,1024,0,stream>>>(src, dst, blkbase, pairs);
  k_bfinal  <<<NBK,256,0,stream>>>(pairs, boff, row_st, inv_sq, csr_src);

  // h_pos = prelu(feat @ Wd + bd)
  k_gemm64t<0,1,0,0,0><<<GB,256,0,stream>>>(feat, Wd, bd, h_pos, nullptr, prelu_a, nullptr, nullptr, nullptr, nullptr);
  // xw1 = h_pos @ Wg1
  k_gemm64t<0,0,0,0,0><<<GB,256,0,stream>>>(h_pos, Wg1, nullptr, xw, nullptr, nullptr, nullptr, nullptr, nullptr, nullptr);
  // embed = gcn1 aggregation (column-split halves)
  k_agg_f32h<<<2*AB,256,0,stream>>>(xw, row_st, csr_src, inv_sq, bg1, embed);
  // score = sigmoid(rowdot(h_pos, sigmoid(embed)@Wbil^T) + bbil)   [fused]
  k_gemm64t<1,0,0,1,0><<<GB,256,0,stream>>>(embed, WbT, nullptr, nullptr, nullptr, nullptr, h_pos, bbil, score, nullptr);
  // top-k: 3-pass LDS-privatized radix select (multi-block) + compacted list
  k_hist<4096,0><<<64,256,0,stream>>>(score, hist0, ctrl);
  k_findb<4096,0><<<1,1024,0,stream>>>(hist0, ctrl);
  k_hist<4096,1><<<64,256,0,stream>>>(score, hist1, ctrl);
  k_findb<4096,1><<<1,1024,0,stream>>>(hist1, ctrl);
  k_hist<256,2><<<64,256,0,stream>>>(score, hist2, ctrl);
  k_findb<256,2><<<1,64,0,stream>>>(hist2, ctrl);
  k_sel<<<NB,256,0,stream>>>(score, ctrl, tie_list, sel, list);
  k_tie<<<1,256,0,stream>>>(ctrl, ctrl, tie_list, sel, list);
  // fine[list] = (gcn2(embed)+bg2)[list] * score[list]   (bf16 xw2, compacted nodes)
  k_gemm64t<0,0,1,0,0><<<GB,256,0,stream>>>(embed, Wg2, nullptr, nullptr, xwb, nullptr, nullptr, nullptr, nullptr, nullptr);
  k_agg_b16<1><<<ABL,256,0,stream>>>((const uint32*)xwb, row_st, csr_src, inv_sq, bg2, fine, score, sel, nullptr, list);
  // out = gcn3(fine) + embed   (bf16 xw3 over selected rows only; MODE2 skips !sel sources)
  k_gemm64t<0,0,1,0,1><<<GBL,256,0,stream>>>(fine, Wg3, nullptr, nullptr, xwb, nullptr, nullptr, nullptr, nullptr, list);
  k_agg_b16<2><<<AB,256,0,stream>>>((const uint32*)xwb, row_st, csr_src, inv_sq, bg3, out, nullptr, sel, embed, nullptr);
}

// Round 12
// 334.664 us; speedup vs baseline: 1.1246x; 1.1232x over previous
//
#include <hip/hip_runtime.h>
#include <hip/hip_bf16.h>

#define NN 50000
#define NE 800000
#define DD 128
#define KSEL 25000
#define NBK 391                 // buckets of 128 nodes (graph build)
#define NBLKA 98                // (NE+8191)/8192
#define AB 12500                // agg node-blocks (4 nodes/block)

typedef unsigned int uint32;
typedef unsigned short ushort16;
typedef __attribute__((ext_vector_type(8))) short bf16x8;
typedef __attribute__((ext_vector_type(4))) float f32x4;

__device__ __forceinline__ float sigmoidf(float x){ return 1.f/(1.f+__expf(-x)); }

__device__ __forceinline__ unsigned short f2b(float f){
  union{float f; unsigned u;} v; v.f=f;
  unsigned r=(v.u + 0x7fffu + ((v.u>>16)&1u))>>16;
  return (unsigned short)r;
}

__device__ __forceinline__ void addbf2(float&lo,float&hi,uint32 u,float w){
  lo+=__uint_as_float(u<<16)*w;
  hi+=__uint_as_float(u&0xffff0000u)*w;
}

// ==== prep: WbT fp32 transpose + bf16-transposed Wg2/Wg3 + zero spans ====
__global__ __launch_bounds__(256) void k_prep(const float* __restrict__ Wbil,
    float* __restrict__ WbT, const float* __restrict__ Wg2, ushort16* __restrict__ Wt2b,
    const float* __restrict__ Wg3, ushort16* __restrict__ Wt3b,
    int* __restrict__ zspan, int* __restrict__ btot){
  int i=blockIdx.x*256+threadIdx.x;      // 64 blocks -> 16384 threads
  if(i<DD*DD){
    int n=i>>7, k=i&127;
    WbT[i]=Wbil[k*DD+n];
    Wt2b[i]=f2b(Wg2[(size_t)k*DD+n]);    // Wt[n][k] = bf16(W[k][n])
    Wt3b[i]=f2b(Wg3[(size_t)k*DD+n]);
  }
  if(i<8512) zspan[i]=0;                 // ctrl(256B)+hist0+hist1+hist2
  if(i<NBK) btot[i]=0;
}

// ================= graph build: bucketed counting sort =================
__global__ __launch_bounds__(1024) void k_bcount(const int* __restrict__ dst,
    int* __restrict__ btot, int* __restrict__ blkcnt){
  __shared__ int h[NBK];
  int tid=threadIdx.x;
  for(int i=tid;i<NBK;i+=1024) h[i]=0;
  __syncthreads();
  int e0=blockIdx.x*8192;
  #pragma unroll
  for(int t=0;t<8;t++){
    int e=e0+t*1024+tid;
    if(e<NE) atomicAdd(&h[dst[e]>>7],1);
  }
  __syncthreads();
  for(int i=tid;i<NBK;i+=1024){
    int c=h[i];
    blkcnt[blockIdx.x*NBK+i]=c;
    if(c) atomicAdd(&btot[i],c);
  }
}

__global__ __launch_bounds__(512) void k_bscan(const int* __restrict__ btot,
    int* __restrict__ boff, const int* __restrict__ blkcnt, int* __restrict__ blkbase,
    int* __restrict__ row_start){
  __shared__ int sdata[512];
  int tid=threadIdx.x;
  int v=(tid<NBK)?btot[tid]:0;
  sdata[tid]=v; __syncthreads();
  for(int off=1;off<512;off<<=1){
    int y=(tid>=off)?sdata[tid-off]:0;
    __syncthreads();
    sdata[tid]+=y;
    __syncthreads();
  }
  int excl=sdata[tid]-v;
  if(tid<NBK) boff[tid]=excl;
  if(tid==NBK-1){ boff[NBK]=excl+v; row_start[NN]=NE; }
  if(tid<NBK){
    int run=excl;
    for(int b=0;b<NBLKA;b++){
      int c=blkcnt[b*NBK+tid];
      blkbase[b*NBK+tid]=run;
      run+=c;
    }
  }
}

// pack: src (17 bits) | local-dst (7 bits) << 17
__global__ __launch_bounds__(1024) void k_bscatter(const int* __restrict__ src,
    const int* __restrict__ dst, const int* __restrict__ blkbase, uint32* __restrict__ pairs){
  __shared__ int cur[NBK];
  int tid=threadIdx.x;
  for(int i=tid;i<NBK;i+=1024) cur[i]=blkbase[blockIdx.x*NBK+i];
  __syncthreads();
  int e0=blockIdx.x*8192;
  #pragma unroll
  for(int t=0;t<8;t++){
    int e=e0+t*1024+tid;
    if(e<NE){
      int d=dst[e];
      int p=atomicAdd(&cur[d>>7],1);
      pairs[p]=(unsigned)src[e] | ((unsigned)(d&127)<<17);
    }
  }
}

__global__ __launch_bounds__(256) void k_bfinal(const uint32* __restrict__ pairs,
    const int* __restrict__ boff, int* __restrict__ row_start,
    float* __restrict__ inv_sq, int* __restrict__ csr_src){
  __shared__ int degl[128];
  __shared__ int cur[128];
  __shared__ int ssum[2];
  int b=blockIdx.x, tid=threadIdx.x;
  int lo=boff[b], hi=boff[b+1];
  if(tid<128) degl[tid]=0;
  __syncthreads();
  for(int e=lo+tid;e<hi;e+=256) atomicAdd(&degl[pairs[e]>>17],1);
  __syncthreads();
  int v=0,x=0;
  if(tid<128){
    v=degl[tid]; x=v;
    #pragma unroll
    for(int off=1;off<64;off<<=1){
      int y=__shfl_up(x,off,64);
      if((tid&63)>=off) x+=y;
    }
    if((tid&63)==63) ssum[tid>>6]=x;
  }
  __syncthreads();
  if(tid<128){
    int incl=x+((tid>=64)?ssum[0]:0);
    int node=b*128+tid;
    int excl=lo+incl-v;
    if(node<NN){
      row_start[node]=excl;
      cur[tid]=excl;
      inv_sq[node]=1.f/sqrtf((float)(v+1));
    }
  }
  __syncthreads();
  for(int e=lo+tid;e<hi;e+=256){
    uint32 u=pairs[e];
    int p=atomicAdd(&cur[u>>17],1);
    csr_src[p]=(int)(u&0x1FFFFu);
  }
}

// ============ fp32 GEMM: 64x128 tile, 4x8 per thread (score path) ============
template<int IN_SIG,int ACT,int FUSE_SCORE>
__global__ __launch_bounds__(256) void k_gemm64t(const float* __restrict__ A,
    const float* __restrict__ W, const float* __restrict__ bias,
    float* __restrict__ outf,
    const float* __restrict__ aparam, const float* __restrict__ hp,
    const float* __restrict__ bbil, float* __restrict__ score){
  __shared__ float Al[64][132];           // 33.8 KB -> 4 blocks/CU
  int tid=threadIdx.x;
  int row0=blockIdx.x*64;
  {
    const float4* A4=(const float4*)(A+(size_t)row0*DD);
    #pragma unroll
    for(int i=0;i<8;i++){
      int idx=i*256+tid;                  // 0..2047
      int r=idx>>5, c=(idx&31)*4;
      float4 v=make_float4(0.f,0.f,0.f,0.f);
      if(row0+r<NN) v=A4[idx];
      if(IN_SIG){ v.x=sigmoidf(v.x); v.y=sigmoidf(v.y); v.z=sigmoidf(v.z); v.w=sigmoidf(v.w); }
      *(float4*)&Al[r][c]=v;
    }
  }
  __syncthreads();
  int tx=tid&15, ty=tid>>4;               // cols tx*8..+7 ; rows ty+16*i (i<4)
  float acc[4][8];
  #pragma unroll
  for(int i=0;i<4;i++)
    #pragma unroll
    for(int c=0;c<8;c++) acc[i][c]=0.f;

  for(int k=0;k<DD;k+=4){
    float wv[4][8];
    #pragma unroll
    for(int r=0;r<4;r++){
      float4 lo=*(const float4*)&W[(size_t)(k+r)*DD+tx*8];
      float4 hi=*(const float4*)&W[(size_t)(k+r)*DD+tx*8+4];
      wv[r][0]=lo.x; wv[r][1]=lo.y; wv[r][2]=lo.z; wv[r][3]=lo.w;
      wv[r][4]=hi.x; wv[r][5]=hi.y; wv[r][6]=hi.z; wv[r][7]=hi.w;
    }
    #pragma unroll
    for(int i=0;i<4;i++){
      float4 a=*(const float4*)&Al[ty+16*i][k];
      #pragma unroll
      for(int c=0;c<8;c++)
        acc[i][c]+=a.x*wv[0][c]+a.y*wv[1][c]+a.z*wv[2][c]+a.w*wv[3][c];
    }
  }

  if(FUSE_SCORE){
    float bb=bbil[0];
    #pragma unroll
    for(int i=0;i<4;i++){
      int r=row0+ty+16*i;
      float p=0.f;
      if(r<NN){
        float4 h0=*(const float4*)&hp[(size_t)r*DD+tx*8];
        float4 h1=*(const float4*)&hp[(size_t)r*DD+tx*8+4];
        p=acc[i][0]*h0.x+acc[i][1]*h0.y+acc[i][2]*h0.z+acc[i][3]*h0.w
         +acc[i][4]*h1.x+acc[i][5]*h1.y+acc[i][6]*h1.z+acc[i][7]*h1.w;
      }
      p+=__shfl_xor(p,1,64); p+=__shfl_xor(p,2,64);
      p+=__shfl_xor(p,4,64); p+=__shfl_xor(p,8,64);
      if(tx==0 && r<NN) score[r]=sigmoidf(p+bb);
    }
    return;
  }
  float bl[8]={0,0,0,0,0,0,0,0};
  if(bias){
    float4 b0=*(const float4*)&bias[tx*8];
    float4 b1=*(const float4*)&bias[tx*8+4];
    bl[0]=b0.x; bl[1]=b0.y; bl[2]=b0.z; bl[3]=b0.w;
    bl[4]=b1.x; bl[5]=b1.y; bl[6]=b1.z; bl[7]=b1.w;
  }
  float ap=ACT?aparam[0]:0.f;
  #pragma unroll
  for(int i=0;i<4;i++){
    int r=row0+ty+16*i;
    if(r<NN){
      float o[8];
      #pragma unroll
      for(int c=0;c<8;c++){
        float t=acc[i][c]+bl[c];
        if(ACT) t=t>=0.f?t:ap*t;
        o[c]=t;
      }
      float4 q0; q0.x=o[0]; q0.y=o[1]; q0.z=o[2]; q0.w=o[3];
      float4 q1; q1.x=o[4]; q1.y=o[5]; q1.z=o[6]; q1.w=o[7];
      *(float4*)&outf[(size_t)r*DD+tx*8]=q0;
      *(float4*)&outf[(size_t)r*DD+tx*8+4]=q1;
    }
  }
}

// ============ bf16 MFMA GEMM: xwb = bf16( bf16(A) @ bf16(W) ) ============
// 64x128 tile, 4 waves, mfma_f32_16x16x32_bf16. W supplied TRANSPOSED bf16.
// Fragment layouts [guide m89/m92]: A: row=lane&15, k=(lane>>4)*8+j (contig 8);
// B(from W^T rows): col=lane&15, same k; C/D: col=lane&15, row=(lane>>4)*4+reg.
template<int ROWLIST>
__global__ __launch_bounds__(256) void k_gemm_mfma(const float* __restrict__ A,
    const ushort16* __restrict__ Wtb, ushort16* __restrict__ outb,
    const int* __restrict__ rlist){
  __shared__ __align__(16) unsigned short Asl[64][136];   // 17.4 KB (pad->2-way, free)
  __shared__ __align__(16) unsigned short Wsl[128][136];  // 34.8 KB
  int tid=threadIdx.x;
  int row0=blockIdx.x*64;
  // stage W^T (already bf16): 2048 x 16B chunks
  {
    const uint4* Wg=(const uint4*)Wtb;
    #pragma unroll
    for(int i=0;i<8;i++){
      int idx=i*256+tid;                 // 0..2047
      int n=idx>>4, k8=(idx&15)*8;
      uint4 v=Wg[idx];
      *(uint4*)&Wsl[n][k8]=v;
    }
  }
  // stage A rows (fp32 -> bf16)
  {
    #pragma unroll
    for(int i=0;i<8;i++){
      int idx=i*256+tid;                 // 0..2047
      int r=idx>>5, c=(idx&31)*4;
      int gr; bool ok;
      if(ROWLIST){ int ri=row0+r; ok=(ri<KSEL); gr=ok?rlist[ri]:0; }
      else { gr=row0+r; ok=(gr<NN); }
      float4 v=make_float4(0.f,0.f,0.f,0.f);
      if(ok) v=*(const float4*)&A[(size_t)gr*DD+c];
      ushort4 pk;
      pk.x=f2b(v.x); pk.y=f2b(v.y); pk.z=f2b(v.z); pk.w=f2b(v.w);
      *(ushort4*)&Asl[r][c]=pk;
    }
  }
  __syncthreads();
  int lane=tid&63, w=tid>>6;
  int lr=lane&15, lk=lane>>4;
  f32x4 acc[8];
  #pragma unroll
  for(int nf=0;nf<8;nf++){ acc[nf][0]=0.f; acc[nf][1]=0.f; acc[nf][2]=0.f; acc[nf][3]=0.f; }
  #pragma unroll
  for(int kk=0;kk<4;kk++){
    int k0=kk*32+lk*8;
    bf16x8 a=*(bf16x8*)&Asl[w*16+lr][k0];
    #pragma unroll
    for(int nf=0;nf<8;nf++){
      bf16x8 b=*(bf16x8*)&Wsl[nf*16+lr][k0];
      acc[nf]=__builtin_amdgcn_mfma_f32_16x16x32_bf16(a,b,acc[nf],0,0,0);
    }
  }
  // write-out: row = w*16 + lk*4 + i ; col = nf*16 + lr
  int orow[4]; bool ok[4];
  #pragma unroll
  for(int i=0;i<4;i++){
    int ri=row0+w*16+lk*4+i;
    if(ROWLIST){ ok[i]=(ri<KSEL); orow[i]=ok[i]?rlist[ri]:0; }
    else { orow[i]=ri; ok[i]=(ri<NN); }
  }
  #pragma unroll
  for(int nf=0;nf<8;nf++){
    int col=nf*16+lr;
    #pragma unroll
    for(int i=0;i<4;i++){
      if(ok[i]) outb[(size_t)orow[i]*DD+col]=f2b(acc[nf][i]);
    }
  }
}

// ---------------- fp32 GCN aggregation: 8-edge unroll (R7-proven) ----------
__global__ __launch_bounds__(256) void k_agg_f32(const float* __restrict__ xw,
    const int* __restrict__ row_start, const int* __restrict__ csr,
    const float* __restrict__ inv, const float* __restrict__ bias,
    float* __restrict__ outp){
  int node=blockIdx.x*4+(threadIdx.x>>6);
  if(node>=NN) return;
  int lane=threadIdx.x&63;
  int g=lane>>5, li=lane&31;
  int rs=row_start[node], re=row_start[node+1];
  float a0=0.f,a1=0.f,a2=0.f,a3=0.f;
  int j=rs;
  for(; j+7<re; j+=8){
    int s0=csr[j+g], s1=csr[j+2+g], s2=csr[j+4+g], s3=csr[j+6+g];
    float w0=inv[s0], w1=inv[s1], w2=inv[s2], w3=inv[s3];
    float4 v0=*(const float4*)&xw[(size_t)s0*DD+li*4];
    float4 v1=*(const float4*)&xw[(size_t)s1*DD+li*4];
    float4 v2=*(const float4*)&xw[(size_t)s2*DD+li*4];
    float4 v3=*(const float4*)&xw[(size_t)s3*DD+li*4];
    a0+=v0.x*w0+v1.x*w1+v2.x*w2+v3.x*w3;
    a1+=v0.y*w0+v1.y*w1+v2.y*w2+v3.y*w3;
    a2+=v0.z*w0+v1.z*w1+v2.z*w2+v3.z*w3;
    a3+=v0.w*w0+v1.w*w1+v2.w*w2+v3.w*w3;
  }
  for(; j+1<re; j+=2){
    int s=csr[j+g];
    float w=inv[s];
    float4 v=*(const float4*)&xw[(size_t)s*DD+li*4];
    a0+=v.x*w; a1+=v.y*w; a2+=v.z*w; a3+=v.w*w;
  }
  if(j<re && g==0){
    int s=csr[j]; float w=inv[s];
    float4 v=*(const float4*)&xw[(size_t)s*DD+li*4];
    a0+=v.x*w; a1+=v.y*w; a2+=v.z*w; a3+=v.w*w;
  }
  if(g==0){
    float wd=inv[node];
    float4 v=*(const float4*)&xw[(size_t)node*DD+li*4];
    a0+=v.x*wd; a1+=v.y*wd; a2+=v.z*wd; a3+=v.w*wd;
  }
  a0+=__shfl_xor(a0,32,64); a1+=__shfl_xor(a1,32,64);
  a2+=__shfl_xor(a2,32,64); a3+=__shfl_xor(a3,32,64);
  if(g==0){
    float wn=inv[node];
    float4 bv=*(const float4*)&bias[li*4];
    float4 o;
    o.x=a0*wn+bv.x; o.y=a1*wn+bv.y; o.z=a2*wn+bv.z; o.w=a3*wn+bv.w;
    *(float4*)&outp[(size_t)node*DD+li*4]=o;
  }
}

// ---------------- bf16 GCN aggregation: 4 edges per dwordx4 --------------
// MODE 1: node = list[i] (all selected): out = (agg+bias)*score
// MODE 2: out = agg(skip !sel[s]) + bias + addbuf
template<int MODE>
__global__ __launch_bounds__(256) void k_agg_b16(const uint32* __restrict__ xwb,
    const int* __restrict__ row_start, const int* __restrict__ csr,
    const float* __restrict__ inv, const float* __restrict__ bias,
    float* __restrict__ outp, const float* __restrict__ score,
    const unsigned char* __restrict__ sel, const float* __restrict__ addbuf,
    const int* __restrict__ list){
  int idx4=blockIdx.x*4+(threadIdx.x>>6);
  int node;
  if(MODE==1){ if(idx4>=KSEL) return; node=list[idx4]; }
  else { node=idx4; if(node>=NN) return; }
  int lane=threadIdx.x&63;
  int g=lane>>4, li=lane&15;
  int rs=row_start[node], re=row_start[node+1];
  float a[8];
  #pragma unroll
  for(int c=0;c<8;c++) a[c]=0.f;
  int j=rs;
  for(; j+7<re; j+=8){
    int sA=csr[j+g], sB=csr[j+4+g];
    if(MODE!=2 || sel[sA]){
      float w=inv[sA];
      uint4 u=*(const uint4*)(xwb+(size_t)sA*64+li*4);
      addbf2(a[0],a[1],u.x,w); addbf2(a[2],a[3],u.y,w);
      addbf2(a[4],a[5],u.z,w); addbf2(a[6],a[7],u.w,w);
    }
    if(MODE!=2 || sel[sB]){
      float w=inv[sB];
      uint4 u=*(const uint4*)(xwb+(size_t)sB*64+li*4);
      addbf2(a[0],a[1],u.x,w); addbf2(a[2],a[3],u.y,w);
      addbf2(a[4],a[5],u.z,w); addbf2(a[6],a[7],u.w,w);
    }
  }
  for(; j+3<re; j+=4){
    int s=csr[j+g];
    if(MODE!=2 || sel[s]){
      float w=inv[s];
      uint4 u=*(const uint4*)(xwb+(size_t)s*64+li*4);
      addbf2(a[0],a[1],u.x,w); addbf2(a[2],a[3],u.y,w);
      addbf2(a[4],a[5],u.z,w); addbf2(a[6],a[7],u.w,w);
    }
  }
  int rem=re-j;
  if(g<rem){
    int s=csr[j+g];
    if(MODE!=2 || sel[s]){
      float w=inv[s];
      uint4 u=*(const uint4*)(xwb+(size_t)s*64+li*4);
      addbf2(a[0],a[1],u.x,w); addbf2(a[2],a[3],u.y,w);
      addbf2(a[4],a[5],u.z,w); addbf2(a[6],a[7],u.w,w);
    }
  }
  if(g==0 && (MODE!=2 || sel[node])){
    float wd=inv[node];
    uint4 u=*(const uint4*)(xwb+(size_t)node*64+li*4);
    addbf2(a[0],a[1],u.x,wd); addbf2(a[2],a[3],u.y,wd);
    addbf2(a[4],a[5],u.z,wd); addbf2(a[6],a[7],u.w,wd);
  }
  #pragma unroll
  for(int c=0;c<8;c++){
    a[c]+=__shfl_xor(a[c],16,64);
    a[c]+=__shfl_xor(a[c],32,64);
  }
  if(g<2){
    float wn=inv[node];
    int cb=li*8+g*4;
    float4 bv=*(const float4*)&bias[cb];
    float r0=a[g*4+0]*wn+bv.x, r1=a[g*4+1]*wn+bv.y;
    float r2=a[g*4+2]*wn+bv.z, r3=a[g*4+3]*wn+bv.w;
    if(MODE==1){
      float sc=score[node];
      r0*=sc; r1*=sc; r2*=sc; r3*=sc;
    } else {
      float4 ad=*(const float4*)&addbuf[(size_t)node*DD+cb];
      r0+=ad.x; r1+=ad.y; r2+=ad.z; r3+=ad.w;
    }
    float4 o; o.x=r0; o.y=r1; o.z=r2; o.w=r3;
    *(float4*)&outp[(size_t)node*DD+cb]=o;
  }
}

// ---------------- 3-pass radix select, LDS-privatized (multi-block) ----------
template<int NB,int PASS>
__global__ __launch_bounds__(256) void k_hist(const float* __restrict__ score,
    int* __restrict__ ghist, const int* __restrict__ ctrl){
  __shared__ int lh[NB];
  int tid=threadIdx.x;
  for(int i=tid;i<NB;i+=256) lh[i]=0;
  __syncthreads();
  int p0=0,p01=0;
  if(PASS==1) p0=ctrl[0];
  if(PASS==2) p01=ctrl[2];
  for(int i=blockIdx.x*256+tid; i<NN; i+=gridDim.x*256){
    unsigned b=__float_as_uint(score[i]);
    if(PASS==0) atomicAdd(&lh[b>>20],1);
    else if(PASS==1){ if((int)(b>>20)==p0) atomicAdd(&lh[(b>>8)&0xFFF],1); }
    else { if((int)(b>>8)==p01) atomicAdd(&lh[b&0xFF],1); }
  }
  __syncthreads();
  for(int i=tid;i<NB;i+=256){ int v=lh[i]; if(v) atomicAdd(&ghist[i],v); }
}

template<int NB,int PASS>
__global__ void k_findb(const int* __restrict__ hist, int* __restrict__ ctrl){
  const int NT=NB/4;
  __shared__ int gsum[NT];
  int t=threadIdx.x;
  int s=hist[t*4]+hist[t*4+1]+hist[t*4+2]+hist[t*4+3];
  int x=s; gsum[t]=x; __syncthreads();
  for(int off=1;off<NT;off<<=1){
    int y=(t+off<NT)?gsum[t+off]:0;
    __syncthreads();
    x+=y; gsum[t]=x; __syncthreads();
  }
  int base;
  if(PASS==0) base=0; else if(PASS==1) base=ctrl[1]; else base=ctrl[3];
  int above=base+((t<NT-1)?gsum[t+1]:0);
  int incl=base+gsum[t];
  if(above<KSEL && incl>=KSEL){
    int c=above, B=0;
    for(int b=3;b>=0;b--){
      int hb=hist[t*4+b];
      if(c+hb>=KSEL){ B=t*4+b; break; }
      c+=hb;
    }
    if(PASS==0){ ctrl[0]=B; ctrl[1]=c; }
    else if(PASS==1){ ctrl[2]=(ctrl[0]<<12)|B; ctrl[3]=c; }
    else { ctrl[4]=(int)((((unsigned)ctrl[2])<<8)|(unsigned)B); ctrl[5]=KSEL-c; }
  }
}

// mark + compacted list build
__global__ void k_sel(const float* __restrict__ score, int* __restrict__ ctrl,
                      int* __restrict__ tie_list, unsigned char* __restrict__ sel,
                      int* __restrict__ list){
  int i=blockIdx.x*256+threadIdx.x;
  if(i>=NN) return;
  unsigned b=__float_as_uint(score[i]);
  unsigned thr=(unsigned)ctrl[4];
  if(b>thr){
    sel[i]=1;
    int p=atomicAdd(&ctrl[7],1);
    list[p]=i;
  }
  else if(b==thr){
    sel[i]=0;
    int p=atomicAdd(&ctrl[6],1);
    if(p<4096) tie_list[p]=i;
  } else sel[i]=0;
}

__global__ __launch_bounds__(256) void k_tie(const int* __restrict__ ctrl_c,
    int* __restrict__ ctrl, const int* __restrict__ tie_list,
    unsigned char* __restrict__ sel, int* __restrict__ list){
  int m=ctrl_c[6]; if(m>4096) m=4096;
  int needed=ctrl_c[5];
  for(int t=threadIdx.x; t<m; t+=blockDim.x){
    int idx=tie_list[t];
    int rank=0;
    for(int j=0;j<m;j++) rank+=(tie_list[j]<idx)?1:0;
    if(rank<needed){
      sel[idx]=1;
      int p=atomicAdd(&ctrl[7],1);
      list[p]=idx;
    }
  }
}

// ============================================================================
extern "C" void kernel_launch(void* const* d_in, const int* in_sizes, int n_in,
                              void* d_out, int out_size, void* d_ws, size_t ws_size,
                              hipStream_t stream){
  const float* feat   =(const float*)d_in[0];
  const int*   ei     =(const int*)  d_in[2];
  const int*   src    = ei;
  const int*   dst    = ei + NE;
  const float* Wd     =(const float*)d_in[3];
  const float* bd     =(const float*)d_in[4];
  const float* prelu_a=(const float*)d_in[5];
  const float* Wbil   =(const float*)d_in[6];
  const float* bbil   =(const float*)d_in[7];
  const float* Wg1    =(const float*)d_in[8];
  const float* bg1    =(const float*)d_in[9];
  const float* Wg2    =(const float*)d_in[10];
  const float* bg2    =(const float*)d_in[11];
  const float* Wg3    =(const float*)d_in[12];
  const float* bg3    =(const float*)d_in[13];
  float* out=(float*)d_out;

  char* p=(char*)d_ws;
  auto alloc=[&](size_t bytes)->void*{ void* r=(void*)p; p+=((bytes+255)/256)*256; return r; };
  float* h_pos   =(float*)alloc((size_t)NN*DD*4);
  float* embed   =(float*)alloc((size_t)NN*DD*4);
  float* xw      =(float*)alloc((size_t)NN*DD*4);   // fp32 xw1 / bf16 xw2,xw3 / pairs (early)
  float* score   =(float*)alloc((size_t)NN*4);
  float* inv_sq  =(float*)alloc((size_t)NN*4);
  float* WbT     =(float*)alloc((size_t)DD*DD*4);
  ushort16* Wt2b =(ushort16*)alloc((size_t)DD*DD*2);
  ushort16* Wt3b =(ushort16*)alloc((size_t)DD*DD*2);
  int*   row_st  =(int*)  alloc((size_t)(NN+1)*4);
  int*   csr_src =(int*)  alloc((size_t)NE*4);
  int*   ctrl    =(int*)  alloc(64);                // contiguous zero-span start
  int*   hist0   =(int*)  alloc(4096*4);
  int*   hist1   =(int*)  alloc(4096*4);
  int*   hist2   =(int*)  alloc(256*4);
  int*   tie_list=(int*)  alloc(4096*4);
  int*   list    =(int*)  alloc((size_t)KSEL*4);
  unsigned char* sel=(unsigned char*)alloc(NN);
  int*   btot    =(int*)  alloc((size_t)NBK*4);
  int*   boff    =(int*)  alloc((size_t)(NBK+1)*4);
  int*   blkcnt  =(int*)  alloc((size_t)NBLKA*NBK*4);
  int*   blkbase =(int*)  alloc((size_t)NBLKA*NBK*4);
  uint32* pairs  =(uint32*)xw;                      // aliased: lifetime before xw1
  ushort16* xwb  =(ushort16*)xw;
  float* fine = out;

  const int NB=(NN+255)/256;
  const int GB=(NN+63)/64;       // 782 blocks (gemm + mfma)
  const int GBL=(KSEL+63)/64;    // 391 compacted mfma blocks
  const int ABL=(KSEL+3)/4;      // 6250 compacted agg blocks

  // prep: transposes (WbT fp32; Wg2/Wg3 -> bf16 transposed) + zero spans
  k_prep<<<64,256,0,stream>>>(Wbil, WbT, Wg2, Wt2b, Wg3, Wt3b, ctrl, btot);

  // graph structure: bucketed counting sort -> CSR + degrees + inv_sqrt
  k_bcount  <<<NBLKA,1024,0,stream>>>(dst, btot, blkcnt);
  k_bscan   <<<1,512,0,stream>>>(btot, boff, blkcnt, blkbase, row_st);
  k_bscatter<<<NBLKA,1024,0,stream>>>(src, dst, blkbase, pairs);
  k_bfinal  <<<NBK,256,0,stream>>>(pairs, boff, row_st, inv_sq, csr_src);

  // h_pos = prelu(feat @ Wd + bd)            [fp32, score path]
  k_gemm64t<0,1,0><<<GB,256,0,stream>>>(feat, Wd, bd, h_pos, prelu_a, nullptr, nullptr, nullptr);
  // xw1 = h_pos @ Wg1                        [fp32, score path]
  k_gemm64t<0,0,0><<<GB,256,0,stream>>>(h_pos, Wg1, nullptr, xw, nullptr, nullptr, nullptr, nullptr);
  // embed = gcn1 aggregation (fp32)
  k_agg_f32<<<AB,256,0,stream>>>(xw, row_st, csr_src, inv_sq, bg1, embed);
  // score = sigmoid(rowdot(h_pos, sigmoid(embed)@Wbil^T) + bbil)   [fused, fp32]
  k_gemm64t<1,0,1><<<GB,256,0,stream>>>(embed, WbT, nullptr, nullptr, nullptr, h_pos, bbil, score);
  // top-k: 3-pass LDS-privatized radix select (multi-block) + compacted list
  k_hist<4096,0><<<64,256,0,stream>>>(score, hist0, ctrl);
  k_findb<4096,0><<<1,1024,0,stream>>>(hist0, ctrl);
  k_hist<4096,1><<<64,256,0,stream>>>(score, hist1, ctrl);
  k_findb<4096,1><<<1,1024,0,stream>>>(hist1, ctrl);
  k_hist<256,2><<<64,256,0,stream>>>(score, hist2, ctrl);
  k_findb<256,2><<<1,64,0,stream>>>(hist2, ctrl);
  k_sel<<<NB,256,0,stream>>>(score, ctrl, tie_list, sel, list);
  k_tie<<<1,256,0,stream>>>(ctrl, ctrl, tie_list, sel, list);
  // xw2 = bf16(embed @ Wg2)                  [MFMA]
  k_gemm_mfma<0><<<GB,256,0,stream>>>(embed, Wt2b, xwb, nullptr);
  k_agg_b16<1><<<ABL,256,0,stream>>>((const uint32*)xwb, row_st, csr_src, inv_sq, bg2, fine, score, sel, nullptr, list);
  // xw3 = bf16(fine @ Wg3) over selected rows [MFMA + ROWLIST]
  k_gemm_mfma<1><<<GBL,256,0,stream>>>(fine, Wt3b, xwb, list);
  k_agg_b16<2><<<AB,256,0,stream>>>((const uint32*)xwb, row_st, csr_src, inv_sq, bg3, out, nullptr, sel, embed, nullptr);
}

// Round 13
// 329.990 us; speedup vs baseline: 1.1406x; 1.0142x over previous
//
#include <hip/hip_runtime.h>
#include <hip/hip_bf16.h>

#define NN 50000
#define NE 800000
#define DD 128
#define KSEL 25000
#define NBK 391                 // buckets of 128 nodes (graph build)
#define NBLKA 98                // (NE+8191)/8192
#define AB 12500                // agg node-blocks (4 nodes/block)

typedef unsigned int uint32;
typedef unsigned short ushort16;
typedef __attribute__((ext_vector_type(8))) short bf16x8;
typedef __attribute__((ext_vector_type(4))) float f32x4;

__device__ __forceinline__ float sigmoidf(float x){ return 1.f/(1.f+__expf(-x)); }

__device__ __forceinline__ unsigned short f2b(float f){
  union{float f; unsigned u;} v; v.f=f;
  unsigned r=(v.u + 0x7fffu + ((v.u>>16)&1u))>>16;
  return (unsigned short)r;
}

__device__ __forceinline__ void addbf2(float&lo,float&hi,uint32 u,float w){
  lo+=__uint_as_float(u<<16)*w;
  hi+=__uint_as_float(u&0xffff0000u)*w;
}

__device__ __forceinline__ int aload(const int* p){
  return __hip_atomic_load(p,__ATOMIC_RELAXED,__HIP_MEMORY_SCOPE_AGENT);
}

// ==== prep: WbT fp32 transpose + bf16-transposed Wg2/Wg3 + zero spans ====
__global__ __launch_bounds__(256) void k_prep(const float* __restrict__ Wbil,
    float* __restrict__ WbT, const float* __restrict__ Wg2, ushort16* __restrict__ Wt2b,
    const float* __restrict__ Wg3, ushort16* __restrict__ Wt3b,
    int* __restrict__ zspan, int* __restrict__ btot){
  int i=blockIdx.x*256+threadIdx.x;      // 64 blocks -> 16384 threads
  if(i<DD*DD){
    int n=i>>7, k=i&127;
    WbT[i]=Wbil[k*DD+n];
    Wt2b[i]=f2b(Wg2[(size_t)k*DD+n]);    // Wt[n][k] = bf16(W[k][n])
    Wt3b[i]=f2b(Wg3[(size_t)k*DD+n]);
  }
  if(i<8512) zspan[i]=0;                 // ctrl(64 ints incl done-counters)+hist0+hist1+hist2
  if(i<NBK) btot[i]=0;
}

// ================= graph build: bucketed counting sort =================
__global__ __launch_bounds__(1024) void k_bcount(const int* __restrict__ dst,
    int* __restrict__ btot, int* __restrict__ blkcnt){
  __shared__ int h[NBK];
  int tid=threadIdx.x;
  for(int i=tid;i<NBK;i+=1024) h[i]=0;
  __syncthreads();
  int e0=blockIdx.x*8192;
  #pragma unroll
  for(int t=0;t<8;t++){
    int e=e0+t*1024+tid;
    if(e<NE) atomicAdd(&h[dst[e]>>7],1);
  }
  __syncthreads();
  for(int i=tid;i<NBK;i+=1024){
    int c=h[i];
    blkcnt[blockIdx.x*NBK+i]=c;
    if(c) atomicAdd(&btot[i],c);
  }
}

__global__ __launch_bounds__(512) void k_bscan(const int* __restrict__ btot,
    int* __restrict__ boff, const int* __restrict__ blkcnt, int* __restrict__ blkbase,
    int* __restrict__ row_start){
  __shared__ int sdata[512];
  int tid=threadIdx.x;
  int v=(tid<NBK)?btot[tid]:0;
  sdata[tid]=v; __syncthreads();
  for(int off=1;off<512;off<<=1){
    int y=(tid>=off)?sdata[tid-off]:0;
    __syncthreads();
    sdata[tid]+=y;
    __syncthreads();
  }
  int excl=sdata[tid]-v;
  if(tid<NBK) boff[tid]=excl;
  if(tid==NBK-1){ boff[NBK]=excl+v; row_start[NN]=NE; }
  if(tid<NBK){
    int run=excl;
    for(int b=0;b<NBLKA;b++){
      int c=blkcnt[b*NBK+tid];
      blkbase[b*NBK+tid]=run;
      run+=c;
    }
  }
}

// pack: src (17 bits) | local-dst (7 bits) << 17
__global__ __launch_bounds__(1024) void k_bscatter(const int* __restrict__ src,
    const int* __restrict__ dst, const int* __restrict__ blkbase, uint32* __restrict__ pairs){
  __shared__ int cur[NBK];
  int tid=threadIdx.x;
  for(int i=tid;i<NBK;i+=1024) cur[i]=blkbase[blockIdx.x*NBK+i];
  __syncthreads();
  int e0=blockIdx.x*8192;
  #pragma unroll
  for(int t=0;t<8;t++){
    int e=e0+t*1024+tid;
    if(e<NE){
      int d=dst[e];
      int p=atomicAdd(&cur[d>>7],1);
      pairs[p]=(unsigned)src[e] | ((unsigned)(d&127)<<17);
    }
  }
}

__global__ __launch_bounds__(256) void k_bfinal(const uint32* __restrict__ pairs,
    const int* __restrict__ boff, int* __restrict__ row_start,
    float* __restrict__ inv_sq, int* __restrict__ csr_src){
  __shared__ int degl[128];
  __shared__ int cur[128];
  __shared__ int ssum[2];
  int b=blockIdx.x, tid=threadIdx.x;
  int lo=boff[b], hi=boff[b+1];
  if(tid<128) degl[tid]=0;
  __syncthreads();
  for(int e=lo+tid;e<hi;e+=256) atomicAdd(&degl[pairs[e]>>17],1);
  __syncthreads();
  int v=0,x=0;
  if(tid<128){
    v=degl[tid]; x=v;
    #pragma unroll
    for(int off=1;off<64;off<<=1){
      int y=__shfl_up(x,off,64);
      if((tid&63)>=off) x+=y;
    }
    if((tid&63)==63) ssum[tid>>6]=x;
  }
  __syncthreads();
  if(tid<128){
    int incl=x+((tid>=64)?ssum[0]:0);
    int node=b*128+tid;
    int excl=lo+incl-v;
    if(node<NN){
      row_start[node]=excl;
      cur[tid]=excl;
      inv_sq[node]=1.f/sqrtf((float)(v+1));
    }
  }
  __syncthreads();
  for(int e=lo+tid;e<hi;e+=256){
    uint32 u=pairs[e];
    int p=atomicAdd(&cur[u>>17],1);
    csr_src[p]=(int)(u&0x1FFFFu);
  }
}

// ============ fp32 GEMM: 64x128 tile, 8 rows x 4 cols per thread ============
// tx in [0,32) -> cols tx*4..+3 ; ty in [0,8) -> rows ty+8*i (i<8).
// A-LDS reads broadcast (2 addrs/wave); W requests halved vs 4x8 mapping.
template<int IN_SIG,int ACT,int FUSE_SCORE>
__global__ __launch_bounds__(256) void k_gemm64t(const float* __restrict__ A,
    const float* __restrict__ W, const float* __restrict__ bias,
    float* __restrict__ outf,
    const float* __restrict__ aparam, const float* __restrict__ hp,
    const float* __restrict__ bbil, float* __restrict__ score){
  __shared__ float Al[64][132];           // 33.8 KB -> 4 blocks/CU
  int tid=threadIdx.x;
  int row0=blockIdx.x*64;
  {
    const float4* A4=(const float4*)(A+(size_t)row0*DD);
    #pragma unroll
    for(int i=0;i<8;i++){
      int idx=i*256+tid;                  // 0..2047
      int r=idx>>5, c=(idx&31)*4;
      float4 v=make_float4(0.f,0.f,0.f,0.f);
      if(row0+r<NN) v=A4[idx];
      if(IN_SIG){ v.x=sigmoidf(v.x); v.y=sigmoidf(v.y); v.z=sigmoidf(v.z); v.w=sigmoidf(v.w); }
      *(float4*)&Al[r][c]=v;
    }
  }
  __syncthreads();
  int tx=tid&31, ty=tid>>5;
  float acc[8][4];
  #pragma unroll
  for(int i=0;i<8;i++)
    #pragma unroll
    for(int c=0;c<4;c++) acc[i][c]=0.f;

  for(int k=0;k<DD;k+=4){
    float4 wv0=*(const float4*)&W[(size_t)(k+0)*DD+tx*4];
    float4 wv1=*(const float4*)&W[(size_t)(k+1)*DD+tx*4];
    float4 wv2=*(const float4*)&W[(size_t)(k+2)*DD+tx*4];
    float4 wv3=*(const float4*)&W[(size_t)(k+3)*DD+tx*4];
    #pragma unroll
    for(int i=0;i<8;i++){
      float4 a=*(const float4*)&Al[ty+8*i][k];
      acc[i][0]+=a.x*wv0.x+a.y*wv1.x+a.z*wv2.x+a.w*wv3.x;
      acc[i][1]+=a.x*wv0.y+a.y*wv1.y+a.z*wv2.y+a.w*wv3.y;
      acc[i][2]+=a.x*wv0.z+a.y*wv1.z+a.z*wv2.z+a.w*wv3.z;
      acc[i][3]+=a.x*wv0.w+a.y*wv1.w+a.z*wv2.w+a.w*wv3.w;
    }
  }

  if(FUSE_SCORE){
    float bb=bbil[0];
    #pragma unroll
    for(int i=0;i<8;i++){
      int r=row0+ty+8*i;
      float p=0.f;
      if(r<NN){
        float4 h=*(const float4*)&hp[(size_t)r*DD+tx*4];
        p=acc[i][0]*h.x+acc[i][1]*h.y+acc[i][2]*h.z+acc[i][3]*h.w;
      }
      // reduce over tx (32 lanes; masks <32 stay within each wave half)
      p+=__shfl_xor(p,16,64); p+=__shfl_xor(p,8,64);
      p+=__shfl_xor(p,4,64);  p+=__shfl_xor(p,2,64); p+=__shfl_xor(p,1,64);
      if(tx==0 && r<NN) score[r]=sigmoidf(p+bb);
    }
    return;
  }
  float4 bv=make_float4(0.f,0.f,0.f,0.f);
  if(bias) bv=*(const float4*)&bias[tx*4];
  float ap=ACT?aparam[0]:0.f;
  #pragma unroll
  for(int i=0;i<8;i++){
    int r=row0+ty+8*i;
    if(r<NN){
      float4 o;
      o.x=acc[i][0]+bv.x; o.y=acc[i][1]+bv.y; o.z=acc[i][2]+bv.z; o.w=acc[i][3]+bv.w;
      if(ACT){
        o.x=o.x>=0.f?o.x:ap*o.x; o.y=o.y>=0.f?o.y:ap*o.y;
        o.z=o.z>=0.f?o.z:ap*o.z; o.w=o.w>=0.f?o.w:ap*o.w;
      }
      *(float4*)&outf[(size_t)r*DD+tx*4]=o;
    }
  }
}

// ============ bf16 MFMA GEMM: xwb = bf16( bf16(A) @ bf16(W) ) ============
template<int ROWLIST>
__global__ __launch_bounds__(256) void k_gemm_mfma(const float* __restrict__ A,
    const ushort16* __restrict__ Wtb, ushort16* __restrict__ outb,
    const int* __restrict__ rlist){
  __shared__ __align__(16) unsigned short Asl[64][136];
  __shared__ __align__(16) unsigned short Wsl[128][136];
  int tid=threadIdx.x;
  int row0=blockIdx.x*64;
  {
    const uint4* Wg=(const uint4*)Wtb;
    #pragma unroll
    for(int i=0;i<8;i++){
      int idx=i*256+tid;
      int n=idx>>4, k8=(idx&15)*8;
      uint4 v=Wg[idx];
      *(uint4*)&Wsl[n][k8]=v;
    }
  }
  {
    #pragma unroll
    for(int i=0;i<8;i++){
      int idx=i*256+tid;
      int r=idx>>5, c=(idx&31)*4;
      int gr; bool ok;
      if(ROWLIST){ int ri=row0+r; ok=(ri<KSEL); gr=ok?rlist[ri]:0; }
      else { gr=row0+r; ok=(gr<NN); }
      float4 v=make_float4(0.f,0.f,0.f,0.f);
      if(ok) v=*(const float4*)&A[(size_t)gr*DD+c];
      ushort4 pk;
      pk.x=f2b(v.x); pk.y=f2b(v.y); pk.z=f2b(v.z); pk.w=f2b(v.w);
      *(ushort4*)&Asl[r][c]=pk;
    }
  }
  __syncthreads();
  int lane=tid&63, w=tid>>6;
  int lr=lane&15, lk=lane>>4;
  f32x4 acc[8];
  #pragma unroll
  for(int nf=0;nf<8;nf++){ acc[nf][0]=0.f; acc[nf][1]=0.f; acc[nf][2]=0.f; acc[nf][3]=0.f; }
  #pragma unroll
  for(int kk=0;kk<4;kk++){
    int k0=kk*32+lk*8;
    bf16x8 a=*(bf16x8*)&Asl[w*16+lr][k0];
    #pragma unroll
    for(int nf=0;nf<8;nf++){
      bf16x8 b=*(bf16x8*)&Wsl[nf*16+lr][k0];
      acc[nf]=__builtin_amdgcn_mfma_f32_16x16x32_bf16(a,b,acc[nf],0,0,0);
    }
  }
  int orow[4]; bool ok[4];
  #pragma unroll
  for(int i=0;i<4;i++){
    int ri=row0+w*16+lk*4+i;
    if(ROWLIST){ ok[i]=(ri<KSEL); orow[i]=ok[i]?rlist[ri]:0; }
    else { orow[i]=ri; ok[i]=(ri<NN); }
  }
  #pragma unroll
  for(int nf=0;nf<8;nf++){
    int col=nf*16+lr;
    #pragma unroll
    for(int i=0;i<4;i++){
      if(ok[i]) outb[(size_t)orow[i]*DD+col]=f2b(acc[nf][i]);
    }
  }
}

// ---------------- fp32 GCN aggregation: 8-edge unroll (R7-proven) ----------
__global__ __launch_bounds__(256) void k_agg_f32(const float* __restrict__ xw,
    const int* __restrict__ row_start, const int* __restrict__ csr,
    const float* __restrict__ inv, const float* __restrict__ bias,
    float* __restrict__ outp){
  int node=blockIdx.x*4+(threadIdx.x>>6);
  if(node>=NN) return;
  int lane=threadIdx.x&63;
  int g=lane>>5, li=lane&31;
  int rs=row_start[node], re=row_start[node+1];
  float a0=0.f,a1=0.f,a2=0.f,a3=0.f;
  int j=rs;
  for(; j+7<re; j+=8){
    int s0=csr[j+g], s1=csr[j+2+g], s2=csr[j+4+g], s3=csr[j+6+g];
    float w0=inv[s0], w1=inv[s1], w2=inv[s2], w3=inv[s3];
    float4 v0=*(const float4*)&xw[(size_t)s0*DD+li*4];
    float4 v1=*(const float4*)&xw[(size_t)s1*DD+li*4];
    float4 v2=*(const float4*)&xw[(size_t)s2*DD+li*4];
    float4 v3=*(const float4*)&xw[(size_t)s3*DD+li*4];
    a0+=v0.x*w0+v1.x*w1+v2.x*w2+v3.x*w3;
    a1+=v0.y*w0+v1.y*w1+v2.y*w2+v3.y*w3;
    a2+=v0.z*w0+v1.z*w1+v2.z*w2+v3.z*w3;
    a3+=v0.w*w0+v1.w*w1+v2.w*w2+v3.w*w3;
  }
  for(; j+1<re; j+=2){
    int s=csr[j+g];
    float w=inv[s];
    float4 v=*(const float4*)&xw[(size_t)s*DD+li*4];
    a0+=v.x*w; a1+=v.y*w; a2+=v.z*w; a3+=v.w*w;
  }
  if(j<re && g==0){
    int s=csr[j]; float w=inv[s];
    float4 v=*(const float4*)&xw[(size_t)s*DD+li*4];
    a0+=v.x*w; a1+=v.y*w; a2+=v.z*w; a3+=v.w*w;
  }
  if(g==0){
    float wd=inv[node];
    float4 v=*(const float4*)&xw[(size_t)node*DD+li*4];
    a0+=v.x*wd; a1+=v.y*wd; a2+=v.z*wd; a3+=v.w*wd;
  }
  a0+=__shfl_xor(a0,32,64); a1+=__shfl_xor(a1,32,64);
  a2+=__shfl_xor(a2,32,64); a3+=__shfl_xor(a3,32,64);
  if(g==0){
    float wn=inv[node];
    float4 bv=*(const float4*)&bias[li*4];
    float4 o;
    o.x=a0*wn+bv.x; o.y=a1*wn+bv.y; o.z=a2*wn+bv.z; o.w=a3*wn+bv.w;
    *(float4*)&outp[(size_t)node*DD+li*4]=o;
  }
}

// ---------------- bf16 GCN aggregation: 4 edges per dwordx4 --------------
template<int MODE>
__global__ __launch_bounds__(256) void k_agg_b16(const uint32* __restrict__ xwb,
    const int* __restrict__ row_start, const int* __restrict__ csr,
    const float* __restrict__ inv, const float* __restrict__ bias,
    float* __restrict__ outp, const float* __restrict__ score,
    const unsigned char* __restrict__ sel, const float* __restrict__ addbuf,
    const int* __restrict__ list){
  int idx4=blockIdx.x*4+(threadIdx.x>>6);
  int node;
  if(MODE==1){ if(idx4>=KSEL) return; node=list[idx4]; }
  else { node=idx4; if(node>=NN) return; }
  int lane=threadIdx.x&63;
  int g=lane>>4, li=lane&15;
  int rs=row_start[node], re=row_start[node+1];
  float a[8];
  #pragma unroll
  for(int c=0;c<8;c++) a[c]=0.f;
  int j=rs;
  for(; j+7<re; j+=8){
    int sA=csr[j+g], sB=csr[j+4+g];
    if(MODE!=2 || sel[sA]){
      float w=inv[sA];
      uint4 u=*(const uint4*)(xwb+(size_t)sA*64+li*4);
      addbf2(a[0],a[1],u.x,w); addbf2(a[2],a[3],u.y,w);
      addbf2(a[4],a[5],u.z,w); addbf2(a[6],a[7],u.w,w);
    }
    if(MODE!=2 || sel[sB]){
      float w=inv[sB];
      uint4 u=*(const uint4*)(xwb+(size_t)sB*64+li*4);
      addbf2(a[0],a[1],u.x,w); addbf2(a[2],a[3],u.y,w);
      addbf2(a[4],a[5],u.z,w); addbf2(a[6],a[7],u.w,w);
    }
  }
  for(; j+3<re; j+=4){
    int s=csr[j+g];
    if(MODE!=2 || sel[s]){
      float w=inv[s];
      uint4 u=*(const uint4*)(xwb+(size_t)s*64+li*4);
      addbf2(a[0],a[1],u.x,w); addbf2(a[2],a[3],u.y,w);
      addbf2(a[4],a[5],u.z,w); addbf2(a[6],a[7],u.w,w);
    }
  }
  int rem=re-j;
  if(g<rem){
    int s=csr[j+g];
    if(MODE!=2 || sel[s]){
      float w=inv[s];
      uint4 u=*(const uint4*)(xwb+(size_t)s*64+li*4);
      addbf2(a[0],a[1],u.x,w); addbf2(a[2],a[3],u.y,w);
      addbf2(a[4],a[5],u.z,w); addbf2(a[6],a[7],u.w,w);
    }
  }
  if(g==0 && (MODE!=2 || sel[node])){
    float wd=inv[node];
    uint4 u=*(const uint4*)(xwb+(size_t)node*64+li*4);
    addbf2(a[0],a[1],u.x,wd); addbf2(a[2],a[3],u.y,wd);
    addbf2(a[4],a[5],u.z,wd); addbf2(a[6],a[7],u.w,wd);
  }
  #pragma unroll
  for(int c=0;c<8;c++){
    a[c]+=__shfl_xor(a[c],16,64);
    a[c]+=__shfl_xor(a[c],32,64);
  }
  if(g<2){
    float wn=inv[node];
    int cb=li*8+g*4;
    float4 bv=*(const float4*)&bias[cb];
    float r0=a[g*4+0]*wn+bv.x, r1=a[g*4+1]*wn+bv.y;
    float r2=a[g*4+2]*wn+bv.z, r3=a[g*4+3]*wn+bv.w;
    if(MODE==1){
      float sc=score[node];
      r0*=sc; r1*=sc; r2*=sc; r3*=sc;
    } else {
      float4 ad=*(const float4*)&addbuf[(size_t)node*DD+cb];
      r0+=ad.x; r1+=ad.y; r2+=ad.z; r3+=ad.w;
    }
    float4 o; o.x=r0; o.y=r1; o.z=r2; o.w=r3;
    *(float4*)&outp[(size_t)node*DD+cb]=o;
  }
}

// ====== 3-pass radix select; findb fused into each hist's LAST block ======
// ctrl: 0:B0 1:c0 2:P01 3:c1 4:thr 5:needed 6:tiecnt 7:listcnt 8..10:done 11:seldone
template<int NB,int PASS>
__global__ __launch_bounds__(256) void k_hist(const float* __restrict__ score,
    int* __restrict__ ghist, int* __restrict__ ctrl){
  __shared__ int lh[NB];
  __shared__ int gs[256];
  __shared__ int lastf;
  int tid=threadIdx.x;
  for(int i=tid;i<NB;i+=256) lh[i]=0;
  __syncthreads();
  int p0=0,p01=0;
  if(PASS==1) p0=ctrl[0];
  if(PASS==2) p01=ctrl[2];
  for(int i=blockIdx.x*256+tid; i<NN; i+=gridDim.x*256){
    unsigned b=__float_as_uint(score[i]);
    if(PASS==0) atomicAdd(&lh[b>>20],1);
    else if(PASS==1){ if((int)(b>>20)==p0) atomicAdd(&lh[(b>>8)&0xFFF],1); }
    else { if((int)(b>>8)==p01) atomicAdd(&lh[b&0xFF],1); }
  }
  __syncthreads();
  for(int i=tid;i<NB;i+=256){ int v=lh[i]; if(v) atomicAdd(&ghist[i],v); }
  __syncthreads();
  if(tid==0){
    __threadfence();
    int v=atomicAdd(&ctrl[8+PASS],1);
    lastf=(v==(int)gridDim.x-1);
  }
  __syncthreads();
  if(!lastf) return;
  // ---- inline findb (256 threads) ----
  const int BPT=NB/256;                  // 16 or 1
  int s=0;
  #pragma unroll
  for(int q=0;q<BPT;q++) s+=aload(&ghist[tid*BPT+q]);
  int x=s; gs[tid]=x; __syncthreads();
  for(int off=1;off<256;off<<=1){
    int y=(tid+off<256)?gs[tid+off]:0;
    __syncthreads(); x+=y; gs[tid]=x; __syncthreads();
  }
  int base;
  if(PASS==0) base=0; else if(PASS==1) base=ctrl[1]; else base=ctrl[3];
  int above=base+x-s, incl=base+x;
  if(above<KSEL && incl>=KSEL){
    int c=above, B=0;
    for(int b=BPT-1;b>=0;b--){
      int hb=aload(&ghist[tid*BPT+b]);
      if(c+hb>=KSEL){ B=tid*BPT+b; break; }
      c+=hb;
    }
    if(PASS==0){ ctrl[0]=B; ctrl[1]=c; }
    else if(PASS==1){ ctrl[2]=(ctrl[0]<<12)|B; ctrl[3]=c; }
    else { ctrl[4]=(int)((((unsigned)ctrl[2])<<8)|(unsigned)B); ctrl[5]=KSEL-c; }
  }
}

// mark + compacted list; tie resolution fused into LAST block
__global__ __launch_bounds__(256) void k_sel(const float* __restrict__ score,
    int* __restrict__ ctrl, int* __restrict__ tie_list,
    unsigned char* __restrict__ sel, int* __restrict__ list){
  __shared__ int lastf;
  int tid=threadIdx.x;
  int i=blockIdx.x*256+tid;
  if(i<NN){
    unsigned b=__float_as_uint(score[i]);
    unsigned thr=(unsigned)ctrl[4];
    if(b>thr){
      sel[i]=1;
      int p=atomicAdd(&ctrl[7],1);
      list[p]=i;
    } else if(b==thr){
      sel[i]=0;
      int p=atomicAdd(&ctrl[6],1);
      if(p<4096) __hip_atomic_store(&tie_list[p],i,__ATOMIC_RELAXED,__HIP_MEMORY_SCOPE_AGENT);
    } else sel[i]=0;
  }
  __syncthreads();
  if(tid==0){
    __threadfence();
    int v=atomicAdd(&ctrl[11],1);
    lastf=(v==(int)gridDim.x-1);
  }
  __syncthreads();
  if(!lastf) return;
  int m=aload(&ctrl[6]); if(m>4096) m=4096;
  int needed=ctrl[5];
  for(int t=tid;t<m;t+=256){
    int idx=aload(&tie_list[t]);
    int rank=0;
    for(int j2=0;j2<m;j2++) rank+=(aload(&tie_list[j2])<idx)?1:0;
    if(rank<needed){
      sel[idx]=1;
      int p=atomicAdd(&ctrl[7],1);
      list[p]=idx;
    }
  }
}

// ============================================================================
extern "C" void kernel_launch(void* const* d_in, const int* in_sizes, int n_in,
                              void* d_out, int out_size, void* d_ws, size_t ws_size,
                              hipStream_t stream){
  const float* feat   =(const float*)d_in[0];
  const int*   ei     =(const int*)  d_in[2];
  const int*   src    = ei;
  const int*   dst    = ei + NE;
  const float* Wd     =(const float*)d_in[3];
  const float* bd     =(const float*)d_in[4];
  const float* prelu_a=(const float*)d_in[5];
  const float* Wbil   =(const float*)d_in[6];
  const float* bbil   =(const float*)d_in[7];
  const float* Wg1    =(const float*)d_in[8];
  const float* bg1    =(const float*)d_in[9];
  const float* Wg2    =(const float*)d_in[10];
  const float* bg2    =(const float*)d_in[11];
  const float* Wg3    =(const float*)d_in[12];
  const float* bg3    =(const float*)d_in[13];
  float* out=(float*)d_out;

  char* p=(char*)d_ws;
  auto alloc=[&](size_t bytes)->void*{ void* r=(void*)p; p+=((bytes+255)/256)*256; return r; };
  float* h_pos   =(float*)alloc((size_t)NN*DD*4);
  float* embed   =(float*)alloc((size_t)NN*DD*4);
  float* xw      =(float*)alloc((size_t)NN*DD*4);   // fp32 xw1 / bf16 xw2,xw3 / pairs (early)
  float* score   =(float*)alloc((size_t)NN*4);
  float* inv_sq  =(float*)alloc((size_t)NN*4);
  float* WbT     =(float*)alloc((size_t)DD*DD*4);
  ushort16* Wt2b =(ushort16*)alloc((size_t)DD*DD*2);
  ushort16* Wt3b =(ushort16*)alloc((size_t)DD*DD*2);
  int*   row_st  =(int*)  alloc((size_t)(NN+1)*4);
  int*   csr_src =(int*)  alloc((size_t)NE*4);
  int*   ctrl    =(int*)  alloc(256);               // 64 ints: state + done counters
  int*   hist0   =(int*)  alloc(4096*4);
  int*   hist1   =(int*)  alloc(4096*4);
  int*   hist2   =(int*)  alloc(256*4);
  int*   tie_list=(int*)  alloc(4096*4);
  int*   list    =(int*)  alloc((size_t)KSEL*4);
  unsigned char* sel=(unsigned char*)alloc(NN);
  int*   btot    =(int*)  alloc((size_t)NBK*4);
  int*   boff    =(int*)  alloc((size_t)(NBK+1)*4);
  int*   blkcnt  =(int*)  alloc((size_t)NBLKA*NBK*4);
  int*   blkbase =(int*)  alloc((size_t)NBLKA*NBK*4);
  uint32* pairs  =(uint32*)xw;                      // aliased: lifetime before xw1
  ushort16* xwb  =(ushort16*)xw;
  float* fine = out;

  const int NB=(NN+255)/256;
  const int GB=(NN+63)/64;       // 782 blocks (gemm + mfma)
  const int GBL=(KSEL+63)/64;    // 391 compacted mfma blocks
  const int ABL=(KSEL+3)/4;      // 6250 compacted agg blocks

  // prep: transposes (WbT fp32; Wg2/Wg3 -> bf16 transposed) + zero spans
  k_prep<<<64,256,0,stream>>>(Wbil, WbT, Wg2, Wt2b, Wg3, Wt3b, ctrl, btot);

  // graph structure: bucketed counting sort -> CSR + degrees + inv_sqrt
  k_bcount  <<<NBLKA,1024,0,stream>>>(dst, btot, blkcnt);
  k_bscan   <<<1,512,0,stream>>>(btot, boff, blkcnt, blkbase, row_st);
  k_bscatter<<<NBLKA,1024,0,stream>>>(src, dst, blkbase, pairs);
  k_bfinal  <<<NBK,256,0,stream>>>(pairs, boff, row_st, inv_sq, csr_src);

  // h_pos = prelu(feat @ Wd + bd)            [fp32, score path]
  k_gemm64t<0,1,0><<<GB,256,0,stream>>>(feat, Wd, bd, h_pos, prelu_a, nullptr, nullptr, nullptr);
  // xw1 = h_pos @ Wg1                        [fp32, score path]
  k_gemm64t<0,0,0><<<GB,256,0,stream>>>(h_pos, Wg1, nullptr, xw, nullptr, nullptr, nullptr, nullptr);
  // embed = gcn1 aggregation (fp32)
  k_agg_f32<<<AB,256,0,stream>>>(xw, row_st, csr_src, inv_sq, bg1, embed);
  // score = sigmoid(rowdot(h_pos, sigmoid(embed)@Wbil^T) + bbil)   [fused, fp32]
  k_gemm64t<1,0,1><<<GB,256,0,stream>>>(embed, WbT, nullptr, nullptr, nullptr, h_pos, bbil, score);
  // top-k: 3 hist dispatches (findb fused into last block) + sel (tie fused)
  k_hist<4096,0><<<64,256,0,stream>>>(score, hist0, ctrl);
  k_hist<4096,1><<<64,256,0,stream>>>(score, hist1, ctrl);
  k_hist<256,2><<<64,256,0,stream>>>(score, hist2, ctrl);
  k_sel<<<NB,256,0,stream>>>(score, ctrl, tie_list, sel, list);
  // xw2 = bf16(embed @ Wg2)                  [MFMA]
  k_gemm_mfma<0><<<GB,256,0,stream>>>(embed, Wt2b, xwb, nullptr);
  k_agg_b16<1><<<ABL,256,0,stream>>>((const uint32*)xwb, row_st, csr_src, inv_sq, bg2, fine, score, sel, nullptr, list);
  // xw3 = bf16(fine @ Wg3) over selected rows [MFMA + ROWLIST]
  k_gemm_mfma<1><<<GBL,256,0,stream>>>(fine, Wt3b, xwb, list);
  k_agg_b16<2><<<AB,256,0,stream>>>((const uint32*)xwb, row_st, csr_src, inv_sq, bg3, out, nullptr, sel, embed, nullptr);
}